// Round 1
// baseline (555.888 us; speedup 1.0000x reference)
//
#include <hip/hip_runtime.h>
#include <hip/hip_bf16.h>

#define NODES 50000
#define NEDGE 800000
#define CH 128          // all of IN/HID/OUT
#define NEG_SLOPE 0.2f

// ---------------------------------------------------------------------------
// edge_index dtype detection: reference makes int64, harness doc says int32.
// If stored as int64 (values < 50000, non-negative), every odd 32-bit word of
// the buffer is 0. Check the first 128 pairs.
// ---------------------------------------------------------------------------
__global__ void detect_i64_kernel(const void* idx, int* flag) {
    const int* w = (const int*)idx;
    int z = 1;
    for (int k = 0; k < 128; ++k)
        if (w[2 * k + 1] != 0) { z = 0; break; }
    *flag = z;
}

__device__ __forceinline__ int edge_at(const void* idx, int i64, int pos) {
    return i64 ? (int)((const long long*)idx)[pos] : ((const int*)idx)[pos];
}

// ---------------------------------------------------------------------------
// CSR build: histogram of dst, exclusive scan, scatter src sorted by dst
// ---------------------------------------------------------------------------
__global__ void hist_kernel(const void* idx, const int* flag, int* cnt) {
    int e = blockIdx.x * blockDim.x + threadIdx.x;
    if (e >= NEDGE) return;
    int dst = edge_at(idx, *flag, NEDGE + e);
    atomicAdd(&cnt[dst], 1);
}

__global__ void scan_kernel(const int* __restrict__ cnt, int* __restrict__ offs,
                            int* __restrict__ cursor) {
    __shared__ int buf[1024];
    __shared__ int carry_s;
    if (threadIdx.x == 0) carry_s = 0;
    __syncthreads();
    for (int base = 0; base < NODES; base += 1024) {
        int i = base + (int)threadIdx.x;
        int v = (i < NODES) ? cnt[i] : 0;
        buf[threadIdx.x] = v;
        __syncthreads();
        for (int ofs = 1; ofs < 1024; ofs <<= 1) {
            int t = (threadIdx.x >= (unsigned)ofs) ? buf[threadIdx.x - ofs] : 0;
            __syncthreads();
            buf[threadIdx.x] += t;
            __syncthreads();
        }
        int incl = buf[threadIdx.x];
        int excl = incl - v + carry_s;       // reads carry before update below
        if (i < NODES) { offs[i] = excl; cursor[i] = excl; }
        __syncthreads();
        if (threadIdx.x == 1023) carry_s += buf[1023];
        __syncthreads();
    }
    if (threadIdx.x == 0) offs[NODES] = carry_s;   // == NEDGE
}

__global__ void scatter_kernel(const void* idx, const int* flag,
                               int* cursor, int* __restrict__ srcs) {
    int e = blockIdx.x * blockDim.x + threadIdx.x;
    if (e >= NEDGE) return;
    int i64 = *flag;
    int s = edge_at(idx, i64, e);
    int d = edge_at(idx, i64, NEDGE + e);
    int pos = atomicAdd(&cursor[d], 1);
    srcs[pos] = s;
}

// ---------------------------------------------------------------------------
// fp32 GEMM: Y[n,128] = X[n,128] @ W[128,128] + b.  64-row tiles in LDS,
// 256 threads, each thread 8 rows x 4 cols.
// ---------------------------------------------------------------------------
#define GR 64
__global__ __launch_bounds__(256) void gemm128(const float* __restrict__ X,
                                               const float* __restrict__ W,
                                               const float* __restrict__ b,
                                               float* __restrict__ Y, int nrows) {
    __shared__ float xs[GR][CH];
    int r0 = blockIdx.x * GR;
    int tid = threadIdx.x;
    int nrow_tile = nrows - r0; if (nrow_tile > GR) nrow_tile = GR;

    const float4* Xv = (const float4*)(X + (size_t)r0 * CH);
    float4* xsv = (float4*)&xs[0][0];
    for (int t = tid; t < nrow_tile * (CH / 4); t += 256) xsv[t] = Xv[t];
    __syncthreads();

    int c0 = (tid & 31) * 4;
    int rbase = (tid >> 5) * 8;
    float acc[8][4];
    #pragma unroll
    for (int r = 0; r < 8; ++r)
        for (int c = 0; c < 4; ++c) acc[r][c] = 0.f;

    for (int k = 0; k < CH; ++k) {
        float4 w = *(const float4*)(W + k * CH + c0);
        #pragma unroll
        for (int r = 0; r < 8; ++r) {
            float xv = xs[rbase + r][k];
            acc[r][0] += xv * w.x;
            acc[r][1] += xv * w.y;
            acc[r][2] += xv * w.z;
            acc[r][3] += xv * w.w;
        }
    }
    float4 bb = *(const float4*)(b + c0);
    #pragma unroll
    for (int r = 0; r < 8; ++r) {
        int rr = r0 + rbase + r;
        if (rr < nrows) {
            float4 o;
            o.x = acc[r][0] + bb.x; o.y = acc[r][1] + bb.y;
            o.z = acc[r][2] + bb.z; o.w = acc[r][3] + bb.w;
            *(float4*)(Y + (size_t)rr * CH + c0) = o;
        }
    }
}

// ---------------------------------------------------------------------------
// Fused GATv2 edge pass: one wave (64 lanes) per destination node.
// lane l owns channels {2l, 2l+1}. GROUP = lanes per attention head
// (16 for heads=4, 64 for heads=1). Online softmax over incoming edges,
// self-loop folded into the initial state.
// ---------------------------------------------------------------------------
template <int GROUP, bool RELU>
__global__ __launch_bounds__(64) void node_pass(
        const float* __restrict__ xl, const float* __restrict__ xr,
        const float* __restrict__ att,    // 128 floats, flat (H, C/H)
        const float* __restrict__ bias,   // 128 floats
        const int* __restrict__ offs, const int* __restrict__ srcs,
        float* __restrict__ out) {
    int i = blockIdx.x;
    int l = threadIdx.x;

    float2 r = ((const float2*)(xr + (size_t)i * CH))[l];
    float2 at = ((const float2*)att)[l];

    // self loop (src = dst = i)
    float2 xs = ((const float2*)(xl + (size_t)i * CH))[l];
    float e0 = xs.x + r.x; e0 = e0 > 0.f ? e0 : NEG_SLOPE * e0;
    float e1 = xs.y + r.y; e1 = e1 > 0.f ? e1 : NEG_SLOPE * e1;
    float t = e0 * at.x + e1 * at.y;
    #pragma unroll
    for (int msk = 1; msk < GROUP; msk <<= 1) t += __shfl_xor(t, msk);

    float m = t;            // running max (per head group, replicated)
    float d = 1.0f;         // running denom
    float acc0 = xs.x, acc1 = xs.y;

    int beg = offs[i], end = offs[i + 1];
    for (int e = beg; e < end; ++e) {
        int s = srcs[e];
        float2 a = ((const float2*)(xl + (size_t)s * CH))[l];
        float f0 = a.x + r.x; f0 = f0 > 0.f ? f0 : NEG_SLOPE * f0;
        float f1 = a.y + r.y; f1 = f1 > 0.f ? f1 : NEG_SLOPE * f1;
        float tt = f0 * at.x + f1 * at.y;
        #pragma unroll
        for (int msk = 1; msk < GROUP; msk <<= 1) tt += __shfl_xor(tt, msk);

        float nm = fmaxf(m, tt);
        float p  = __expf(tt - nm);
        float sc = __expf(m - nm);
        d    = d * sc + p;
        acc0 = acc0 * sc + p * a.x;
        acc1 = acc1 * sc + p * a.y;
        m = nm;
    }

    float inv = 1.0f / d;
    float2 bb = ((const float2*)bias)[l];
    float o0 = acc0 * inv + bb.x;
    float o1 = acc1 * inv + bb.y;
    if (RELU) { o0 = fmaxf(o0, 0.f); o1 = fmaxf(o1, 0.f); }
    ((float2*)(out + (size_t)i * CH))[l] = make_float2(o0, o1);
}

// ---------------------------------------------------------------------------
extern "C" void kernel_launch(void* const* d_in, const int* in_sizes, int n_in,
                              void* d_out, int out_size, void* d_ws, size_t ws_size,
                              hipStream_t stream) {
    const float* x     = (const float*)d_in[0];
    const void*  eidx  = d_in[1];
    const float* W1l   = (const float*)d_in[2];
    const float* b1l   = (const float*)d_in[3];
    const float* W1r   = (const float*)d_in[4];
    const float* b1r   = (const float*)d_in[5];
    const float* att1  = (const float*)d_in[6];
    const float* bias1 = (const float*)d_in[7];
    const float* W2l   = (const float*)d_in[8];
    const float* b2l   = (const float*)d_in[9];
    const float* W2r   = (const float*)d_in[10];
    const float* b2r   = (const float*)d_in[11];
    const float* att2  = (const float*)d_in[12];
    const float* bias2 = (const float*)d_in[13];
    float* out = (float*)d_out;

    // workspace layout
    float* xl = (float*)d_ws;                       // N*128
    float* xr = xl + (size_t)NODES * CH;            // N*128
    float* hb = xr + (size_t)NODES * CH;            // N*128
    int* offs   = (int*)(hb + (size_t)NODES * CH);  // N+1
    int* cnt    = offs + (NODES + 1);               // N
    int* cursor = cnt + NODES;                      // N
    int* srcs   = cursor + NODES;                   // E
    int* flag   = srcs + NEDGE;                     // 1

    const int EB = 256, EG = (NEDGE + EB - 1) / EB;
    const int GG = (NODES + GR - 1) / GR;

    // CSR build
    hipMemsetAsync(cnt, 0, (size_t)NODES * sizeof(int), stream);
    detect_i64_kernel<<<1, 1, 0, stream>>>(eidx, flag);
    hist_kernel<<<EG, EB, 0, stream>>>(eidx, flag, cnt);
    scan_kernel<<<1, 1024, 0, stream>>>(cnt, offs, cursor);
    scatter_kernel<<<EG, EB, 0, stream>>>(eidx, flag, cursor, srcs);

    // layer 1
    gemm128<<<GG, 256, 0, stream>>>(x, W1l, b1l, xl, NODES);
    gemm128<<<GG, 256, 0, stream>>>(x, W1r, b1r, xr, NODES);
    node_pass<16, true><<<NODES, 64, 0, stream>>>(xl, xr, att1, bias1, offs, srcs, hb);

    // layer 2
    gemm128<<<GG, 256, 0, stream>>>(hb, W2l, b2l, xl, NODES);
    gemm128<<<GG, 256, 0, stream>>>(hb, W2r, b2r, xr, NODES);
    node_pass<64, false><<<NODES, 64, 0, stream>>>(xl, xr, att2, bias2, offs, srcs, out);
}

// Round 2
// 530.351 us; speedup vs baseline: 1.0482x; 1.0482x over previous
//
#include <hip/hip_runtime.h>
#include <hip/hip_bf16.h>

#define NODES 50000
#define NEDGE 800000
#define CH 128          // all of IN/HID/OUT
#define NEG_SLOPE 0.2f
#define SCAN_CHUNK 2048
#define NBLK ((NODES + SCAN_CHUNK - 1) / SCAN_CHUNK)   // 25

// ---------------------------------------------------------------------------
// edge_index dtype detection (int64 vs int32): if int64 with values < 2^31,
// every odd 32-bit word is 0. One wave checks 64 pairs via ballot.
// ---------------------------------------------------------------------------
__global__ void detect_i64_kernel(const void* idx, int* flag) {
    const int* w = (const int*)idx;
    int nz = (w[2 * threadIdx.x + 1] != 0) ? 1 : 0;
    unsigned long long b = __ballot(nz);
    if (threadIdx.x == 0) *flag = (b == 0ull) ? 1 : 0;
}

__device__ __forceinline__ int edge_at(const void* idx, int i64, int pos) {
    return i64 ? (int)((const long long*)idx)[pos] : ((const int*)idx)[pos];
}

// ---------------------------------------------------------------------------
// CSR build: histogram of dst, 3-phase parallel exclusive scan, scatter src
// ---------------------------------------------------------------------------
__global__ void hist_kernel(const void* idx, const int* flag, int* cnt) {
    int e = blockIdx.x * blockDim.x + threadIdx.x;
    if (e >= NEDGE) return;
    int dst = edge_at(idx, *flag, NEDGE + e);
    atomicAdd(&cnt[dst], 1);
}

// phase 1: per-block (2048-elem chunk) totals
__global__ __launch_bounds__(256) void scan1_kernel(const int* __restrict__ cnt,
                                                    int* __restrict__ bsum) {
    int base = blockIdx.x * SCAN_CHUNK + (int)threadIdx.x * 8;
    int s = 0;
    #pragma unroll
    for (int k = 0; k < 8; ++k) {
        int i = base + k;
        s += (i < NODES) ? cnt[i] : 0;
    }
    #pragma unroll
    for (int m = 1; m < 64; m <<= 1) s += __shfl_xor(s, m);
    __shared__ int ws[4];
    if ((threadIdx.x & 63) == 0) ws[threadIdx.x >> 6] = s;
    __syncthreads();
    if (threadIdx.x == 0) bsum[blockIdx.x] = ws[0] + ws[1] + ws[2] + ws[3];
}

// phase 2: serial scan of NBLK (=25) block sums
__global__ void scan2_kernel(const int* __restrict__ bsum, int* __restrict__ boff,
                             int* __restrict__ offs) {
    if (threadIdx.x == 0) {
        int acc = 0;
        for (int b = 0; b < NBLK; ++b) { boff[b] = acc; acc += bsum[b]; }
        offs[NODES] = acc;      // == NEDGE
    }
}

// phase 3: per-block exclusive scan + global offset
__global__ __launch_bounds__(256) void scan3_kernel(const int* __restrict__ cnt,
                                                    const int* __restrict__ boff,
                                                    int* __restrict__ offs,
                                                    int* __restrict__ cursor) {
    int tid = (int)threadIdx.x;
    int base = blockIdx.x * SCAN_CHUNK + tid * 8;
    int v[8];
    int s = 0;
    #pragma unroll
    for (int k = 0; k < 8; ++k) {
        int i = base + k;
        v[k] = (i < NODES) ? cnt[i] : 0;
        s += v[k];
    }
    int lane = tid & 63;
    int incl = s;
    #pragma unroll
    for (int m = 1; m < 64; m <<= 1) {
        int t = __shfl_up(incl, m);
        if (lane >= m) incl += t;
    }
    __shared__ int wtot[4];
    if (lane == 63) wtot[tid >> 6] = incl;
    __syncthreads();
    int w = tid >> 6;
    int wbase = 0;
    #pragma unroll
    for (int k = 0; k < 4; ++k) wbase += (k < w) ? wtot[k] : 0;
    int excl = boff[blockIdx.x] + wbase + (incl - s);
    #pragma unroll
    for (int k = 0; k < 8; ++k) {
        int i = base + k;
        if (i < NODES) { offs[i] = excl; cursor[i] = excl; }
        excl += v[k];
    }
}

__global__ void scatter_kernel(const void* idx, const int* flag,
                               int* cursor, int* __restrict__ srcs) {
    int e = blockIdx.x * blockDim.x + threadIdx.x;
    if (e >= NEDGE) return;
    int i64 = *flag;
    int s = edge_at(idx, i64, e);
    int d = edge_at(idx, i64, NEDGE + e);
    int pos = atomicAdd(&cursor[d], 1);
    srcs[pos] = s;
}

// ---------------------------------------------------------------------------
// Fused dual fp32 GEMM: Yl = X@Wl + bl, Yr = X@Wr + br in one pass.
// 64-row tile staged once in LDS; 256 threads; each thread 8 rows x 8 cols
// (lanes 0-15 of each wave-half cover Wl's 128 cols, lanes 16-31 Wr's).
// k unrolled x4 with ds_read_b128 so the LDS pipe is not the bottleneck.
// ---------------------------------------------------------------------------
#define GR 64
__global__ __launch_bounds__(256) void gemm_dual(const float* __restrict__ X,
                                                 const float* __restrict__ Wl,
                                                 const float* __restrict__ bl,
                                                 const float* __restrict__ Wr,
                                                 const float* __restrict__ br,
                                                 float* __restrict__ Yl,
                                                 float* __restrict__ Yr, int nrows) {
    __shared__ float xs[GR][CH];   // 32 KiB
    int r0 = blockIdx.x * GR;
    int tid = (int)threadIdx.x;
    int ntile = nrows - r0; if (ntile > GR) ntile = GR;

    const float4* Xv = (const float4*)(X + (size_t)r0 * CH);
    float4* xsv = (float4*)&xs[0][0];
    for (int t = tid; t < ntile * (CH / 4); t += 256) xsv[t] = Xv[t];
    __syncthreads();

    int c0 = (tid & 31) * 8;             // 0..248 over [Wl cols | Wr cols]
    const float* W; const float* bias; float* Y; int cc;
    if (c0 < CH) { W = Wl; bias = bl; Y = Yl; cc = c0; }
    else         { W = Wr; bias = br; Y = Yr; cc = c0 - CH; }
    int rbase = (tid >> 5) * 8;

    float acc[8][8];
    #pragma unroll
    for (int r = 0; r < 8; ++r)
        #pragma unroll
        for (int c = 0; c < 8; ++c) acc[r][c] = 0.f;

    for (int k = 0; k < CH; k += 4) {
        float4 xv[8];
        #pragma unroll
        for (int r = 0; r < 8; ++r) xv[r] = *(const float4*)&xs[rbase + r][k];
        #pragma unroll
        for (int kk = 0; kk < 4; ++kk) {
            float4 w0 = *(const float4*)(W + (size_t)(k + kk) * CH + cc);
            float4 w1 = *(const float4*)(W + (size_t)(k + kk) * CH + cc + 4);
            #pragma unroll
            for (int r = 0; r < 8; ++r) {
                float xk = ((const float*)&xv[r])[kk];
                acc[r][0] += xk * w0.x; acc[r][1] += xk * w0.y;
                acc[r][2] += xk * w0.z; acc[r][3] += xk * w0.w;
                acc[r][4] += xk * w1.x; acc[r][5] += xk * w1.y;
                acc[r][6] += xk * w1.z; acc[r][7] += xk * w1.w;
            }
        }
    }

    float4 b0 = *(const float4*)(bias + cc);
    float4 b1 = *(const float4*)(bias + cc + 4);
    #pragma unroll
    for (int r = 0; r < 8; ++r) {
        int rr = r0 + rbase + r;
        if (rr < nrows) {
            float4 o0, o1;
            o0.x = acc[r][0] + b0.x; o0.y = acc[r][1] + b0.y;
            o0.z = acc[r][2] + b0.z; o0.w = acc[r][3] + b0.w;
            o1.x = acc[r][4] + b1.x; o1.y = acc[r][5] + b1.y;
            o1.z = acc[r][6] + b1.z; o1.w = acc[r][7] + b1.w;
            *(float4*)(Y + (size_t)rr * CH + cc)     = o0;
            *(float4*)(Y + (size_t)rr * CH + cc + 4) = o1;
        }
    }
}

// ---------------------------------------------------------------------------
// Fused GATv2 edge pass: one wave per destination node, lane l owns channels
// {2l, 2l+1}. GROUP = lanes per head (16 for heads=4, 64 for heads=1).
// Online softmax; self-loop folded into initial state.
// ---------------------------------------------------------------------------
template <int GROUP, bool RELU>
__global__ __launch_bounds__(64) void node_pass(
        const float* __restrict__ xl, const float* __restrict__ xr,
        const float* __restrict__ att,    // 128 floats, flat (H, C/H)
        const float* __restrict__ bias,   // 128 floats
        const int* __restrict__ offs, const int* __restrict__ srcs,
        float* __restrict__ out) {
    int i = blockIdx.x;
    int l = threadIdx.x;

    float2 r = ((const float2*)(xr + (size_t)i * CH))[l];
    float2 at = ((const float2*)att)[l];

    // self loop (src = dst = i)
    float2 xs = ((const float2*)(xl + (size_t)i * CH))[l];
    float e0 = xs.x + r.x; e0 = e0 > 0.f ? e0 : NEG_SLOPE * e0;
    float e1 = xs.y + r.y; e1 = e1 > 0.f ? e1 : NEG_SLOPE * e1;
    float t = e0 * at.x + e1 * at.y;
    #pragma unroll
    for (int msk = 1; msk < GROUP; msk <<= 1) t += __shfl_xor(t, msk);

    float m = t;            // running max (replicated within head group)
    float d = 1.0f;         // running denom
    float acc0 = xs.x, acc1 = xs.y;

    int beg = offs[i], end = offs[i + 1];
    for (int e = beg; e < end; ++e) {
        int s = srcs[e];
        float2 a = ((const float2*)(xl + (size_t)s * CH))[l];
        float f0 = a.x + r.x; f0 = f0 > 0.f ? f0 : NEG_SLOPE * f0;
        float f1 = a.y + r.y; f1 = f1 > 0.f ? f1 : NEG_SLOPE * f1;
        float tt = f0 * at.x + f1 * at.y;
        #pragma unroll
        for (int msk = 1; msk < GROUP; msk <<= 1) tt += __shfl_xor(tt, msk);

        float nm = fmaxf(m, tt);
        float p  = __expf(tt - nm);
        float sc = __expf(m - nm);
        d    = d * sc + p;
        acc0 = acc0 * sc + p * a.x;
        acc1 = acc1 * sc + p * a.y;
        m = nm;
    }

    float inv = 1.0f / d;
    float2 bb = ((const float2*)bias)[l];
    float o0 = acc0 * inv + bb.x;
    float o1 = acc1 * inv + bb.y;
    if (RELU) { o0 = fmaxf(o0, 0.f); o1 = fmaxf(o1, 0.f); }
    ((float2*)(out + (size_t)i * CH))[l] = make_float2(o0, o1);
}

// ---------------------------------------------------------------------------
extern "C" void kernel_launch(void* const* d_in, const int* in_sizes, int n_in,
                              void* d_out, int out_size, void* d_ws, size_t ws_size,
                              hipStream_t stream) {
    const float* x     = (const float*)d_in[0];
    const void*  eidx  = d_in[1];
    const float* W1l   = (const float*)d_in[2];
    const float* b1l   = (const float*)d_in[3];
    const float* W1r   = (const float*)d_in[4];
    const float* b1r   = (const float*)d_in[5];
    const float* att1  = (const float*)d_in[6];
    const float* bias1 = (const float*)d_in[7];
    const float* W2l   = (const float*)d_in[8];
    const float* b2l   = (const float*)d_in[9];
    const float* W2r   = (const float*)d_in[10];
    const float* b2r   = (const float*)d_in[11];
    const float* att2  = (const float*)d_in[12];
    const float* bias2 = (const float*)d_in[13];
    float* out = (float*)d_out;

    // workspace layout
    float* xl = (float*)d_ws;                       // N*128
    float* xr = xl + (size_t)NODES * CH;            // N*128
    float* hb = xr + (size_t)NODES * CH;            // N*128
    int* offs   = (int*)(hb + (size_t)NODES * CH);  // N+1
    int* cnt    = offs + (NODES + 1);               // N
    int* cursor = cnt + NODES;                      // N
    int* srcs   = cursor + NODES;                   // E
    int* flag   = srcs + NEDGE;                     // 1
    int* bsum   = flag + 1;                         // NBLK
    int* boff   = bsum + NBLK;                      // NBLK

    const int EB = 256, EG = (NEDGE + EB - 1) / EB;
    const int GG = (NODES + GR - 1) / GR;

    // CSR build
    hipMemsetAsync(cnt, 0, (size_t)NODES * sizeof(int), stream);
    detect_i64_kernel<<<1, 64, 0, stream>>>(eidx, flag);
    hist_kernel<<<EG, EB, 0, stream>>>(eidx, flag, cnt);
    scan1_kernel<<<NBLK, 256, 0, stream>>>(cnt, bsum);
    scan2_kernel<<<1, 64, 0, stream>>>(bsum, boff, offs);
    scan3_kernel<<<NBLK, 256, 0, stream>>>(cnt, boff, offs, cursor);
    scatter_kernel<<<EG, EB, 0, stream>>>(eidx, flag, cursor, srcs);

    // layer 1
    gemm_dual<<<GG, 256, 0, stream>>>(x, W1l, b1l, W1r, b1r, xl, xr, NODES);
    node_pass<16, true><<<NODES, 64, 0, stream>>>(xl, xr, att1, bias1, offs, srcs, hb);

    // layer 2
    gemm_dual<<<GG, 256, 0, stream>>>(hb, W2l, b2l, W2r, b2r, xl, xr, NODES);
    node_pass<64, false><<<NODES, 64, 0, stream>>>(xl, xr, att2, bias2, offs, srcs, out);
}

// Round 3
// 454.405 us; speedup vs baseline: 1.2233x; 1.1671x over previous
//
#include <hip/hip_runtime.h>
#include <hip/hip_bf16.h>

#define NODES 50000
#define NEDGE 800000
#define CH 128          // all of IN/HID/OUT
#define NEG_SLOPE 0.2f
#define SCAN_CHUNK 2048
#define NBLK ((NODES + SCAN_CHUNK - 1) / SCAN_CHUNK)   // 25

typedef short short8 __attribute__((ext_vector_type(8)));
typedef float f32x4 __attribute__((ext_vector_type(4)));

// fp32 -> bf16 (RNE) and back, as raw ushort bits
__device__ __forceinline__ unsigned short f2bf(float f) {
    union { float f; unsigned u; } v; v.f = f;
    unsigned r = v.u + 0x7fff + ((v.u >> 16) & 1);
    return (unsigned short)(r >> 16);
}
__device__ __forceinline__ float bf2f(unsigned short h) {
    union { float f; unsigned u; } v; v.u = ((unsigned)h) << 16;
    return v.f;
}

// ---------------------------------------------------------------------------
// edge_index dtype detection (int64 vs int32)
// ---------------------------------------------------------------------------
__global__ void detect_i64_kernel(const void* idx, int* flag) {
    const int* w = (const int*)idx;
    int nz = (w[2 * threadIdx.x + 1] != 0) ? 1 : 0;
    unsigned long long b = __ballot(nz);
    if (threadIdx.x == 0) *flag = (b == 0ull) ? 1 : 0;
}

__device__ __forceinline__ int edge_at(const void* idx, int i64, int pos) {
    return i64 ? (int)((const long long*)idx)[pos] : ((const int*)idx)[pos];
}

// ---------------------------------------------------------------------------
// CSR build: histogram of dst, 3-phase parallel exclusive scan, scatter src
// ---------------------------------------------------------------------------
__global__ void hist_kernel(const void* idx, const int* flag, int* cnt) {
    int e = blockIdx.x * blockDim.x + threadIdx.x;
    if (e >= NEDGE) return;
    int dst = edge_at(idx, *flag, NEDGE + e);
    atomicAdd(&cnt[dst], 1);
}

__global__ __launch_bounds__(256) void scan1_kernel(const int* __restrict__ cnt,
                                                    int* __restrict__ bsum) {
    int base = blockIdx.x * SCAN_CHUNK + (int)threadIdx.x * 8;
    int s = 0;
    #pragma unroll
    for (int k = 0; k < 8; ++k) {
        int i = base + k;
        s += (i < NODES) ? cnt[i] : 0;
    }
    #pragma unroll
    for (int m = 1; m < 64; m <<= 1) s += __shfl_xor(s, m);
    __shared__ int ws[4];
    if ((threadIdx.x & 63) == 0) ws[threadIdx.x >> 6] = s;
    __syncthreads();
    if (threadIdx.x == 0) bsum[blockIdx.x] = ws[0] + ws[1] + ws[2] + ws[3];
}

__global__ void scan2_kernel(const int* __restrict__ bsum, int* __restrict__ boff,
                             int* __restrict__ offs) {
    if (threadIdx.x == 0) {
        int acc = 0;
        for (int b = 0; b < NBLK; ++b) { boff[b] = acc; acc += bsum[b]; }
        offs[NODES] = acc;      // == NEDGE
    }
}

__global__ __launch_bounds__(256) void scan3_kernel(const int* __restrict__ cnt,
                                                    const int* __restrict__ boff,
                                                    int* __restrict__ offs,
                                                    int* __restrict__ cursor) {
    int tid = (int)threadIdx.x;
    int base = blockIdx.x * SCAN_CHUNK + tid * 8;
    int v[8];
    int s = 0;
    #pragma unroll
    for (int k = 0; k < 8; ++k) {
        int i = base + k;
        v[k] = (i < NODES) ? cnt[i] : 0;
        s += v[k];
    }
    int lane = tid & 63;
    int incl = s;
    #pragma unroll
    for (int m = 1; m < 64; m <<= 1) {
        int t = __shfl_up(incl, m);
        if (lane >= m) incl += t;
    }
    __shared__ int wtot[4];
    if (lane == 63) wtot[tid >> 6] = incl;
    __syncthreads();
    int w = tid >> 6;
    int wbase = 0;
    #pragma unroll
    for (int k = 0; k < 4; ++k) wbase += (k < w) ? wtot[k] : 0;
    int excl = boff[blockIdx.x] + wbase + (incl - s);
    #pragma unroll
    for (int k = 0; k < 8; ++k) {
        int i = base + k;
        if (i < NODES) { offs[i] = excl; cursor[i] = excl; }
        excl += v[k];
    }
}

__global__ void scatter_kernel(const void* idx, const int* flag,
                               int* cursor, int* __restrict__ srcs) {
    int e = blockIdx.x * blockDim.x + threadIdx.x;
    if (e >= NEDGE) return;
    int i64 = *flag;
    int s = edge_at(idx, i64, e);
    int d = edge_at(idx, i64, NEDGE + e);
    int pos = atomicAdd(&cursor[d], 1);
    srcs[pos] = s;
}

// ---------------------------------------------------------------------------
// W prep: W[128x128] fp32 row-major [k][n] -> transposed [n][k] bf16 hi/lo
// ---------------------------------------------------------------------------
__global__ __launch_bounds__(256) void wprep_kernel(const float* __restrict__ W,
                                                    unsigned short* __restrict__ hiT,
                                                    unsigned short* __restrict__ loT) {
    int i = blockIdx.x * 256 + (int)threadIdx.x;   // 0..16383
    if (i >= CH * CH) return;
    int k = i >> 7, n = i & 127;
    float f = W[i];
    unsigned short h = f2bf(f);
    unsigned short l = f2bf(f - bf2f(h));
    hiT[n * CH + k] = h;
    loT[n * CH + k] = l;
}

// ---------------------------------------------------------------------------
// Split-bf16 MFMA dual GEMM: Yl = X@Wl + bl, Yr = X@Wr + br.
// X (fp32) staged to LDS as hi/lo bf16 once per 64-row block tile; W given
// pre-transposed [n][k] hi/lo bf16 (L2-hot). X@W = Xh@Wh + Xl@Wh + Xh@Wl.
// Block = 4 waves; wave w covers n-cols [w*64, w*64+64) of the 256-wide
// [Yl|Yr] output; each wave: 4 Mtiles x 4 Ntiles of 16x16, K=128 in 4 steps.
// ---------------------------------------------------------------------------
#define GR 64
#define LDP 136   // padded row stride in shorts (+8 to spread LDS banks)

__global__ __launch_bounds__(256) void gemm_dual_mfma(
        const float* __restrict__ X,
        const unsigned short* __restrict__ whTl, const unsigned short* __restrict__ wlTl,
        const unsigned short* __restrict__ whTr, const unsigned short* __restrict__ wlTr,
        const float* __restrict__ bl, const float* __restrict__ br,
        float* __restrict__ Yl, float* __restrict__ Yr, int nrows) {
    __shared__ unsigned short xh[GR][LDP];
    __shared__ unsigned short xlo[GR][LDP];

    int r0 = blockIdx.x * GR;
    int tid = (int)threadIdx.x;

    // ---- stage X tile: fp32 -> hi/lo bf16 in LDS ----
    {
        int row = tid >> 2;              // 0..63
        int c0 = (tid & 3) * 32;         // col start
        const float* src = X + (size_t)(r0 + row) * CH + c0;
        bool valid = (r0 + row) < nrows;
        #pragma unroll
        for (int j = 0; j < 32; j += 4) {
            float4 v = valid ? *(const float4*)(src + j)
                             : make_float4(0.f, 0.f, 0.f, 0.f);
            float fv[4] = {v.x, v.y, v.z, v.w};
            #pragma unroll
            for (int c = 0; c < 4; ++c) {
                unsigned short h = f2bf(fv[c]);
                xh[row][c0 + j + c]  = h;
                xlo[row][c0 + j + c] = f2bf(fv[c] - bf2f(h));
            }
        }
    }
    __syncthreads();

    int wave = tid >> 6;      // 0..3: n-quarter
    int lane = tid & 63;
    int l15 = lane & 15, q = lane >> 4;

    f32x4 acc[4][4];
    #pragma unroll
    for (int mt = 0; mt < 4; ++mt)
        #pragma unroll
        for (int nt = 0; nt < 4; ++nt) acc[mt][nt] = (f32x4)0.f;

    // per-lane B row pointers (fixed n per nt)
    const unsigned short* bhp[4];
    const unsigned short* blp_[4];
    int ncol[4];
    #pragma unroll
    for (int nt = 0; nt < 4; ++nt) {
        int n = (wave * 4 + nt) * 16 + l15;       // 0..255
        ncol[nt] = n;
        int nn = n & 127;
        bhp[nt]  = ((n < CH) ? whTl : whTr) + (size_t)nn * CH;
        blp_[nt] = ((n < CH) ? wlTl : wlTr) + (size_t)nn * CH;
    }

    for (int kt = 0; kt < 4; ++kt) {
        int kofs = kt * 32 + q * 8;
        short8 ah[4], al[4];
        #pragma unroll
        for (int mt = 0; mt < 4; ++mt) {
            ah[mt] = *(const short8*)&xh[mt * 16 + l15][kofs];
            al[mt] = *(const short8*)&xlo[mt * 16 + l15][kofs];
        }
        #pragma unroll
        for (int nt = 0; nt < 4; ++nt) {
            short8 bh8 = *(const short8*)(bhp[nt] + kofs);
            short8 bl8 = *(const short8*)(blp_[nt] + kofs);
            #pragma unroll
            for (int mt = 0; mt < 4; ++mt) {
                acc[mt][nt] = __builtin_amdgcn_mfma_f32_16x16x32_bf16(
                                  ah[mt], bh8, acc[mt][nt], 0, 0, 0);
                acc[mt][nt] = __builtin_amdgcn_mfma_f32_16x16x32_bf16(
                                  al[mt], bh8, acc[mt][nt], 0, 0, 0);
                acc[mt][nt] = __builtin_amdgcn_mfma_f32_16x16x32_bf16(
                                  ah[mt], bl8, acc[mt][nt], 0, 0, 0);
            }
        }
    }

    // ---- epilogue: C/D layout col=lane&15, row=q*4+reg ----
    #pragma unroll
    for (int nt = 0; nt < 4; ++nt) {
        int n = ncol[nt];
        float* Y = (n < CH) ? Yl : Yr;
        int nc = n & 127;
        float bv = (n < CH) ? bl[nc] : br[nc];
        #pragma unroll
        for (int mt = 0; mt < 4; ++mt) {
            #pragma unroll
            for (int reg = 0; reg < 4; ++reg) {
                int row = r0 + mt * 16 + q * 4 + reg;
                if (row < nrows)
                    Y[(size_t)row * CH + nc] = acc[mt][nt][reg] + bv;
            }
        }
    }
}

// ---------------------------------------------------------------------------
// Fused GATv2 edge pass: one wave per destination node, lane l owns channels
// {2l, 2l+1}. GROUP = lanes per head (16 for heads=4, 64 for heads=1).
// Online softmax; self-loop folded into initial state.
// ---------------------------------------------------------------------------
template <int GROUP, bool RELU>
__global__ __launch_bounds__(64) void node_pass(
        const float* __restrict__ xl, const float* __restrict__ xr,
        const float* __restrict__ att,    // 128 floats, flat (H, C/H)
        const float* __restrict__ bias,   // 128 floats
        const int* __restrict__ offs, const int* __restrict__ srcs,
        float* __restrict__ out) {
    int i = blockIdx.x;
    int l = threadIdx.x;

    float2 r = ((const float2*)(xr + (size_t)i * CH))[l];
    float2 at = ((const float2*)att)[l];

    // self loop (src = dst = i)
    float2 xs = ((const float2*)(xl + (size_t)i * CH))[l];
    float e0 = xs.x + r.x; e0 = e0 > 0.f ? e0 : NEG_SLOPE * e0;
    float e1 = xs.y + r.y; e1 = e1 > 0.f ? e1 : NEG_SLOPE * e1;
    float t = e0 * at.x + e1 * at.y;
    #pragma unroll
    for (int msk = 1; msk < GROUP; msk <<= 1) t += __shfl_xor(t, msk);

    float m = t;            // running max (replicated within head group)
    float d = 1.0f;         // running denom
    float acc0 = xs.x, acc1 = xs.y;

    int beg = offs[i], end = offs[i + 1];
    for (int e = beg; e < end; ++e) {
        int s = srcs[e];
        float2 a = ((const float2*)(xl + (size_t)s * CH))[l];
        float f0 = a.x + r.x; f0 = f0 > 0.f ? f0 : NEG_SLOPE * f0;
        float f1 = a.y + r.y; f1 = f1 > 0.f ? f1 : NEG_SLOPE * f1;
        float tt = f0 * at.x + f1 * at.y;
        #pragma unroll
        for (int msk = 1; msk < GROUP; msk <<= 1) tt += __shfl_xor(tt, msk);

        float nm = fmaxf(m, tt);
        float p  = __expf(tt - nm);
        float sc = __expf(m - nm);
        d    = d * sc + p;
        acc0 = acc0 * sc + p * a.x;
        acc1 = acc1 * sc + p * a.y;
        m = nm;
    }

    float inv = 1.0f / d;
    float2 bb = ((const float2*)bias)[l];
    float o0 = acc0 * inv + bb.x;
    float o1 = acc1 * inv + bb.y;
    if (RELU) { o0 = fmaxf(o0, 0.f); o1 = fmaxf(o1, 0.f); }
    ((float2*)(out + (size_t)i * CH))[l] = make_float2(o0, o1);
}

// ---------------------------------------------------------------------------
extern "C" void kernel_launch(void* const* d_in, const int* in_sizes, int n_in,
                              void* d_out, int out_size, void* d_ws, size_t ws_size,
                              hipStream_t stream) {
    const float* x     = (const float*)d_in[0];
    const void*  eidx  = d_in[1];
    const float* W1l   = (const float*)d_in[2];
    const float* b1l   = (const float*)d_in[3];
    const float* W1r   = (const float*)d_in[4];
    const float* b1r   = (const float*)d_in[5];
    const float* att1  = (const float*)d_in[6];
    const float* bias1 = (const float*)d_in[7];
    const float* W2l   = (const float*)d_in[8];
    const float* b2l   = (const float*)d_in[9];
    const float* W2r   = (const float*)d_in[10];
    const float* b2r   = (const float*)d_in[11];
    const float* att2  = (const float*)d_in[12];
    const float* bias2 = (const float*)d_in[13];
    float* out = (float*)d_out;

    // workspace layout
    float* xl = (float*)d_ws;                       // N*128
    float* xr = xl + (size_t)NODES * CH;            // N*128
    float* hb = xr + (size_t)NODES * CH;            // N*128
    int* offs   = (int*)(hb + (size_t)NODES * CH);  // N+1
    int* cnt    = offs + (NODES + 1);               // N  (reused as W bf16 buf)
    int* cursor = cnt + NODES;                      // N  (reused as W bf16 buf)
    int* srcs   = cursor + NODES;                   // E
    int* flag   = srcs + NEDGE;                     // 1
    int* bsum   = flag + 1;                         // NBLK
    int* boff   = bsum + NBLK;                      // NBLK

    // After scatter, cnt+cursor (400 KB) are dead -> reuse for bf16 W's.
    // Layout: per W (4 of them): hi[16384] then lo[16384] shorts.
    unsigned short* wbuf = (unsigned short*)cnt;
    unsigned short* w1lh = wbuf;              unsigned short* w1ll = wbuf + 16384;
    unsigned short* w1rh = wbuf + 32768;      unsigned short* w1rl = wbuf + 49152;
    unsigned short* w2lh = wbuf + 65536;      unsigned short* w2ll = wbuf + 81920;
    unsigned short* w2rh = wbuf + 98304;      unsigned short* w2rl = wbuf + 114688;

    const int EB = 256, EG = (NEDGE + EB - 1) / EB;
    const int GG = (NODES + GR - 1) / GR;
    const int WG = (CH * CH + 255) / 256;     // 64

    // CSR build
    hipMemsetAsync(cnt, 0, (size_t)NODES * sizeof(int), stream);
    detect_i64_kernel<<<1, 64, 0, stream>>>(eidx, flag);
    hist_kernel<<<EG, EB, 0, stream>>>(eidx, flag, cnt);
    scan1_kernel<<<NBLK, 256, 0, stream>>>(cnt, bsum);
    scan2_kernel<<<1, 64, 0, stream>>>(bsum, boff, offs);
    scan3_kernel<<<NBLK, 256, 0, stream>>>(cnt, boff, offs, cursor);
    scatter_kernel<<<EG, EB, 0, stream>>>(eidx, flag, cursor, srcs);

    // W -> bf16 hi/lo transposed (cnt/cursor are dead now)
    wprep_kernel<<<WG, 256, 0, stream>>>(W1l, w1lh, w1ll);
    wprep_kernel<<<WG, 256, 0, stream>>>(W1r, w1rh, w1rl);
    wprep_kernel<<<WG, 256, 0, stream>>>(W2l, w2lh, w2ll);
    wprep_kernel<<<WG, 256, 0, stream>>>(W2r, w2rh, w2rl);

    // layer 1
    gemm_dual_mfma<<<GG, 256, 0, stream>>>(x, w1lh, w1ll, w1rh, w1rl,
                                           b1l, b1r, xl, xr, NODES);
    node_pass<16, true><<<NODES, 64, 0, stream>>>(xl, xr, att1, bias1, offs, srcs, hb);

    // layer 2
    gemm_dual_mfma<<<GG, 256, 0, stream>>>(hb, w2lh, w2ll, w2rh, w2rl,
                                           b2l, b2r, xl, xr, NODES);
    node_pass<64, false><<<NODES, 64, 0, stream>>>(xl, xr, att2, bias2, offs, srcs, out);
}

// Round 4
// 413.343 us; speedup vs baseline: 1.3449x; 1.0993x over previous
//
#include <hip/hip_runtime.h>
#include <hip/hip_bf16.h>

#define NODES 50000
#define NEDGE 800000
#define CH 128          // all of IN/HID/OUT
#define NEG_SLOPE 0.2f
#define SCAN_CHUNK 2048
#define NBLK ((NODES + SCAN_CHUNK - 1) / SCAN_CHUNK)   // 25
#define NINF -1.0e30f

typedef short short8 __attribute__((ext_vector_type(8)));
typedef float f32x4 __attribute__((ext_vector_type(4)));

// fp32 -> bf16 (RNE) and back, as raw ushort bits
__device__ __forceinline__ unsigned short f2bf(float f) {
    union { float f; unsigned u; } v; v.f = f;
    unsigned r = v.u + 0x7fff + ((v.u >> 16) & 1);
    return (unsigned short)(r >> 16);
}
__device__ __forceinline__ float bf2f(unsigned short h) {
    union { float f; unsigned u; } v; v.u = ((unsigned)h) << 16;
    return v.f;
}
__device__ __forceinline__ float lrelu(float x) {
    return fmaxf(x, 0.f) + NEG_SLOPE * fminf(x, 0.f);
}

// ---------------------------------------------------------------------------
// edge_index dtype detection (int64 vs int32)
// ---------------------------------------------------------------------------
__global__ void detect_i64_kernel(const void* idx, int* flag) {
    const int* w = (const int*)idx;
    int nz = (w[2 * threadIdx.x + 1] != 0) ? 1 : 0;
    unsigned long long b = __ballot(nz);
    if (threadIdx.x == 0) *flag = (b == 0ull) ? 1 : 0;
}

__device__ __forceinline__ int edge_at(const void* idx, int i64, int pos) {
    return i64 ? (int)((const long long*)idx)[pos] : ((const int*)idx)[pos];
}

// ---------------------------------------------------------------------------
// CSR build: histogram of dst, 3-phase parallel exclusive scan, scatter src
// ---------------------------------------------------------------------------
__global__ void hist_kernel(const void* idx, const int* flag, int* cnt) {
    int e = blockIdx.x * blockDim.x + threadIdx.x;
    if (e >= NEDGE) return;
    int dst = edge_at(idx, *flag, NEDGE + e);
    atomicAdd(&cnt[dst], 1);
}

__global__ __launch_bounds__(256) void scan1_kernel(const int* __restrict__ cnt,
                                                    int* __restrict__ bsum) {
    int base = blockIdx.x * SCAN_CHUNK + (int)threadIdx.x * 8;
    int s = 0;
    #pragma unroll
    for (int k = 0; k < 8; ++k) {
        int i = base + k;
        s += (i < NODES) ? cnt[i] : 0;
    }
    #pragma unroll
    for (int m = 1; m < 64; m <<= 1) s += __shfl_xor(s, m);
    __shared__ int ws[4];
    if ((threadIdx.x & 63) == 0) ws[threadIdx.x >> 6] = s;
    __syncthreads();
    if (threadIdx.x == 0) bsum[blockIdx.x] = ws[0] + ws[1] + ws[2] + ws[3];
}

__global__ void scan2_kernel(const int* __restrict__ bsum, int* __restrict__ boff,
                             int* __restrict__ offs) {
    if (threadIdx.x == 0) {
        int acc = 0;
        for (int b = 0; b < NBLK; ++b) { boff[b] = acc; acc += bsum[b]; }
        offs[NODES] = acc;      // == NEDGE
    }
}

__global__ __launch_bounds__(256) void scan3_kernel(const int* __restrict__ cnt,
                                                    const int* __restrict__ boff,
                                                    int* __restrict__ offs,
                                                    int* __restrict__ cursor) {
    int tid = (int)threadIdx.x;
    int base = blockIdx.x * SCAN_CHUNK + tid * 8;
    int v[8];
    int s = 0;
    #pragma unroll
    for (int k = 0; k < 8; ++k) {
        int i = base + k;
        v[k] = (i < NODES) ? cnt[i] : 0;
        s += v[k];
    }
    int lane = tid & 63;
    int incl = s;
    #pragma unroll
    for (int m = 1; m < 64; m <<= 1) {
        int t = __shfl_up(incl, m);
        if (lane >= m) incl += t;
    }
    __shared__ int wtot[4];
    if (lane == 63) wtot[tid >> 6] = incl;
    __syncthreads();
    int w = tid >> 6;
    int wbase = 0;
    #pragma unroll
    for (int k = 0; k < 4; ++k) wbase += (k < w) ? wtot[k] : 0;
    int excl = boff[blockIdx.x] + wbase + (incl - s);
    #pragma unroll
    for (int k = 0; k < 8; ++k) {
        int i = base + k;
        if (i < NODES) { offs[i] = excl; cursor[i] = excl; }
        excl += v[k];
    }
}

__global__ void scatter_kernel(const void* idx, const int* flag,
                               int* cursor, int* __restrict__ srcs) {
    int e = blockIdx.x * blockDim.x + threadIdx.x;
    if (e >= NEDGE) return;
    int i64 = *flag;
    int s = edge_at(idx, i64, e);
    int d = edge_at(idx, i64, NEDGE + e);
    int pos = atomicAdd(&cursor[d], 1);
    srcs[pos] = s;
}

// ---------------------------------------------------------------------------
// W prep (all 4 W's in one launch): fp32 [k][n] -> transposed [n][k] bf16
// hi/lo. Per W: hi[16384] then lo[16384] shorts at stride 32768.
// ---------------------------------------------------------------------------
__global__ __launch_bounds__(256) void wprep4_kernel(const float* __restrict__ W0,
                                                     const float* __restrict__ W1,
                                                     const float* __restrict__ W2,
                                                     const float* __restrict__ W3,
                                                     unsigned short* __restrict__ base) {
    int which = blockIdx.x >> 6;                 // 64 blocks per W
    const float* W = (which == 0) ? W0 : (which == 1) ? W1 : (which == 2) ? W2 : W3;
    unsigned short* hiT = base + (size_t)which * 32768;
    unsigned short* loT = hiT + 16384;
    int i = (blockIdx.x & 63) * 256 + (int)threadIdx.x;   // 0..16383
    int k = i >> 7, n = i & 127;
    float f = W[i];
    unsigned short h = f2bf(f);
    unsigned short l = f2bf(f - bf2f(h));
    hiT[n * CH + k] = h;
    loT[n * CH + k] = l;
}

// ---------------------------------------------------------------------------
// Split-bf16 MFMA dual GEMM: Yl = X@Wl + bl, Yr = X@Wr + br.
// X@W = Xh@Wh + Xl@Wh + Xh@Wl (lo@lo dropped, ~2^-18).
// ---------------------------------------------------------------------------
#define GR 64
#define LDP 136   // padded row stride in shorts

__global__ __launch_bounds__(256) void gemm_dual_mfma(
        const float* __restrict__ X,
        const unsigned short* __restrict__ whTl, const unsigned short* __restrict__ wlTl,
        const unsigned short* __restrict__ whTr, const unsigned short* __restrict__ wlTr,
        const float* __restrict__ bl, const float* __restrict__ br,
        float* __restrict__ Yl, float* __restrict__ Yr, int nrows) {
    __shared__ unsigned short xh[GR][LDP];
    __shared__ unsigned short xlo[GR][LDP];

    int r0 = blockIdx.x * GR;
    int tid = (int)threadIdx.x;

    // ---- stage X tile: fp32 -> hi/lo bf16 in LDS ----
    {
        int row = tid >> 2;              // 0..63
        int c0 = (tid & 3) * 32;         // col start
        const float* src = X + (size_t)(r0 + row) * CH + c0;
        bool valid = (r0 + row) < nrows;
        #pragma unroll
        for (int j = 0; j < 32; j += 4) {
            float4 v = valid ? *(const float4*)(src + j)
                             : make_float4(0.f, 0.f, 0.f, 0.f);
            float fv[4] = {v.x, v.y, v.z, v.w};
            #pragma unroll
            for (int c = 0; c < 4; ++c) {
                unsigned short h = f2bf(fv[c]);
                xh[row][c0 + j + c]  = h;
                xlo[row][c0 + j + c] = f2bf(fv[c] - bf2f(h));
            }
        }
    }
    __syncthreads();

    int wave = tid >> 6;      // 0..3: n-quarter
    int lane = tid & 63;
    int l15 = lane & 15, q = lane >> 4;

    f32x4 acc[4][4];
    #pragma unroll
    for (int mt = 0; mt < 4; ++mt)
        #pragma unroll
        for (int nt = 0; nt < 4; ++nt) acc[mt][nt] = (f32x4)0.f;

    const unsigned short* bhp[4];
    const unsigned short* blp_[4];
    int ncol[4];
    #pragma unroll
    for (int nt = 0; nt < 4; ++nt) {
        int n = (wave * 4 + nt) * 16 + l15;       // 0..255
        ncol[nt] = n;
        int nn = n & 127;
        bhp[nt]  = ((n < CH) ? whTl : whTr) + (size_t)nn * CH;
        blp_[nt] = ((n < CH) ? wlTl : wlTr) + (size_t)nn * CH;
    }

    for (int kt = 0; kt < 4; ++kt) {
        int kofs = kt * 32 + q * 8;
        short8 ah[4], al[4];
        #pragma unroll
        for (int mt = 0; mt < 4; ++mt) {
            ah[mt] = *(const short8*)&xh[mt * 16 + l15][kofs];
            al[mt] = *(const short8*)&xlo[mt * 16 + l15][kofs];
        }
        #pragma unroll
        for (int nt = 0; nt < 4; ++nt) {
            short8 bh8 = *(const short8*)(bhp[nt] + kofs);
            short8 bl8 = *(const short8*)(blp_[nt] + kofs);
            #pragma unroll
            for (int mt = 0; mt < 4; ++mt) {
                acc[mt][nt] = __builtin_amdgcn_mfma_f32_16x16x32_bf16(
                                  ah[mt], bh8, acc[mt][nt], 0, 0, 0);
                acc[mt][nt] = __builtin_amdgcn_mfma_f32_16x16x32_bf16(
                                  al[mt], bh8, acc[mt][nt], 0, 0, 0);
                acc[mt][nt] = __builtin_amdgcn_mfma_f32_16x16x32_bf16(
                                  ah[mt], bl8, acc[mt][nt], 0, 0, 0);
            }
        }
    }

    // ---- epilogue: C/D layout col=lane&15, row=q*4+reg ----
    #pragma unroll
    for (int nt = 0; nt < 4; ++nt) {
        int n = ncol[nt];
        float* Y = (n < CH) ? Yl : Yr;
        int nc = n & 127;
        float bv = (n < CH) ? bl[nc] : br[nc];
        #pragma unroll
        for (int mt = 0; mt < 4; ++mt) {
            #pragma unroll
            for (int reg = 0; reg < 4; ++reg) {
                int row = r0 + mt * 16 + q * 4 + reg;
                if (row < nrows)
                    Y[(size_t)row * CH + nc] = acc[mt][nt][reg] + bv;
            }
        }
    }
}

// ---------------------------------------------------------------------------
// Fused GATv2 edge pass, v2: 4 waves/block, one node per wave.
// 32 lanes cover an edge row (float4/lane); the two 32-lane halves of a wave
// run independent online-softmax states over interleaved edge pairs (4 edges
// in flight per wave iteration), merged at the end via shfl_xor(...,32).
// HEADS=4 -> 8-lane logit butterfly; HEADS=1 -> 32-lane.
// ---------------------------------------------------------------------------
template <int HEADS, bool RELU>
__global__ __launch_bounds__(256) void node_pass(
        const float* __restrict__ xl, const float* __restrict__ xr,
        const float* __restrict__ att,    // 128 floats, flat (H, C/H)
        const float* __restrict__ bias,   // 128 floats
        const int* __restrict__ offs, const int* __restrict__ srcs,
        float* __restrict__ out) {
    constexpr int GL = (CH / HEADS) / 4;     // lanes per head group: 8 or 32
    int wave = (int)threadIdx.x >> 6;
    int i = blockIdx.x * 4 + wave;
    int lane = (int)threadIdx.x & 63;
    int half = lane >> 5;
    int l32 = lane & 31;

    float4 r  = ((const float4*)(xr + (size_t)i * CH))[l32];
    float4 at = ((const float4*)att)[l32];
    float4 xs = ((const float4*)(xl + (size_t)i * CH))[l32];

    // self-loop logit (both halves compute; only half 0 folds it)
    float ts = lrelu(xs.x + r.x) * at.x + lrelu(xs.y + r.y) * at.y
             + lrelu(xs.z + r.z) * at.z + lrelu(xs.w + r.w) * at.w;
    #pragma unroll
    for (int msk = 1; msk < GL; msk <<= 1) ts += __shfl_xor(ts, msk);

    float  m = (half == 0) ? ts : NINF;
    float  d = (half == 0) ? 1.f : 0.f;
    float4 acc;
    acc.x = (half == 0) ? xs.x : 0.f;  acc.y = (half == 0) ? xs.y : 0.f;
    acc.z = (half == 0) ? xs.z : 0.f;  acc.w = (half == 0) ? xs.w : 0.f;

    int beg = offs[i], end = offs[i + 1];
    int deg = end - beg;
    int iters = (deg + 3) >> 2;
    int e0 = beg + half * 2;
    for (int it = 0; it < iters; ++it, e0 += 4) {
        int ea = e0, eb = e0 + 1;
        bool va = ea < end, vb = eb < end;
        int sa = srcs[min(ea, end - 1)];
        int sb = srcs[min(eb, end - 1)];
        float4 a0 = ((const float4*)(xl + (size_t)sa * CH))[l32];
        float4 a1 = ((const float4*)(xl + (size_t)sb * CH))[l32];

        float t0 = lrelu(a0.x + r.x) * at.x + lrelu(a0.y + r.y) * at.y
                 + lrelu(a0.z + r.z) * at.z + lrelu(a0.w + r.w) * at.w;
        float t1 = lrelu(a1.x + r.x) * at.x + lrelu(a1.y + r.y) * at.y
                 + lrelu(a1.z + r.z) * at.z + lrelu(a1.w + r.w) * at.w;
        #pragma unroll
        for (int msk = 1; msk < GL; msk <<= 1) {
            t0 += __shfl_xor(t0, msk);
            t1 += __shfl_xor(t1, msk);
        }
        t0 = va ? t0 : NINF;
        t1 = vb ? t1 : NINF;

        float nm = fmaxf(m, fmaxf(t0, t1));
        float sc = __expf(m - nm);
        float p0 = va ? __expf(t0 - nm) : 0.f;
        float p1 = vb ? __expf(t1 - nm) : 0.f;
        d = d * sc + p0 + p1;
        acc.x = acc.x * sc + p0 * a0.x + p1 * a1.x;
        acc.y = acc.y * sc + p0 * a0.y + p1 * a1.y;
        acc.z = acc.z * sc + p0 * a0.z + p1 * a1.z;
        acc.w = acc.w * sc + p0 * a0.w + p1 * a1.w;
        m = nm;
    }

    // merge the two half-wave states (symmetric; both halves compute same)
    float mo = __shfl_xor(m, 32);
    float do_ = __shfl_xor(d, 32);
    float4 ao;
    ao.x = __shfl_xor(acc.x, 32); ao.y = __shfl_xor(acc.y, 32);
    ao.z = __shfl_xor(acc.z, 32); ao.w = __shfl_xor(acc.w, 32);
    float mt = fmaxf(m, mo);
    float s0 = __expf(m - mt), s1 = __expf(mo - mt);
    float dt = d * s0 + do_ * s1;
    float inv = 1.0f / dt;

    float4 bb = ((const float4*)bias)[l32];
    float4 ot;
    ot.x = (acc.x * s0 + ao.x * s1) * inv + bb.x;
    ot.y = (acc.y * s0 + ao.y * s1) * inv + bb.y;
    ot.z = (acc.z * s0 + ao.z * s1) * inv + bb.z;
    ot.w = (acc.w * s0 + ao.w * s1) * inv + bb.w;
    if (RELU) {
        ot.x = fmaxf(ot.x, 0.f); ot.y = fmaxf(ot.y, 0.f);
        ot.z = fmaxf(ot.z, 0.f); ot.w = fmaxf(ot.w, 0.f);
    }
    if (half == 0)
        ((float4*)(out + (size_t)i * CH))[l32] = ot;
}

// ---------------------------------------------------------------------------
extern "C" void kernel_launch(void* const* d_in, const int* in_sizes, int n_in,
                              void* d_out, int out_size, void* d_ws, size_t ws_size,
                              hipStream_t stream) {
    const float* x     = (const float*)d_in[0];
    const void*  eidx  = d_in[1];
    const float* W1l   = (const float*)d_in[2];
    const float* b1l   = (const float*)d_in[3];
    const float* W1r   = (const float*)d_in[4];
    const float* b1r   = (const float*)d_in[5];
    const float* att1  = (const float*)d_in[6];
    const float* bias1 = (const float*)d_in[7];
    const float* W2l   = (const float*)d_in[8];
    const float* b2l   = (const float*)d_in[9];
    const float* W2r   = (const float*)d_in[10];
    const float* b2r   = (const float*)d_in[11];
    const float* att2  = (const float*)d_in[12];
    const float* bias2 = (const float*)d_in[13];
    float* out = (float*)d_out;

    // workspace layout
    float* xl = (float*)d_ws;                       // N*128
    float* xr = xl + (size_t)NODES * CH;            // N*128
    float* hb = xr + (size_t)NODES * CH;            // N*128
    int* offs   = (int*)(hb + (size_t)NODES * CH);  // N+1
    int* cnt    = offs + (NODES + 1);               // N  (reused as W bf16 buf)
    int* cursor = cnt + NODES;                      // N  (reused as W bf16 buf)
    int* srcs   = cursor + NODES;                   // E
    int* flag   = srcs + NEDGE;                     // 1
    int* bsum   = flag + 1;                         // NBLK
    int* boff   = bsum + NBLK;                      // NBLK

    // After scatter, cnt+cursor (400 KB) are dead -> reuse for bf16 W's.
    unsigned short* wbuf = (unsigned short*)cnt;
    unsigned short* w1lh = wbuf;              unsigned short* w1ll = wbuf + 16384;
    unsigned short* w1rh = wbuf + 32768;      unsigned short* w1rl = wbuf + 49152;
    unsigned short* w2lh = wbuf + 65536;      unsigned short* w2ll = wbuf + 81920;
    unsigned short* w2rh = wbuf + 98304;      unsigned short* w2rl = wbuf + 114688;

    const int EB = 256, EG = (NEDGE + EB - 1) / EB;
    const int GG = (NODES + GR - 1) / GR;

    // CSR build
    hipMemsetAsync(cnt, 0, (size_t)NODES * sizeof(int), stream);
    detect_i64_kernel<<<1, 64, 0, stream>>>(eidx, flag);
    hist_kernel<<<EG, EB, 0, stream>>>(eidx, flag, cnt);
    scan1_kernel<<<NBLK, 256, 0, stream>>>(cnt, bsum);
    scan2_kernel<<<1, 64, 0, stream>>>(bsum, boff, offs);
    scan3_kernel<<<NBLK, 256, 0, stream>>>(cnt, boff, offs, cursor);
    scatter_kernel<<<EG, EB, 0, stream>>>(eidx, flag, cursor, srcs);

    // W -> bf16 hi/lo transposed (cnt/cursor dead after scatter)
    wprep4_kernel<<<256, 256, 0, stream>>>(W1l, W1r, W2l, W2r, wbuf);

    // layer 1
    gemm_dual_mfma<<<GG, 256, 0, stream>>>(x, w1lh, w1ll, w1rh, w1rl,
                                           b1l, b1r, xl, xr, NODES);
    node_pass<4, true><<<(NODES + 3) / 4, 256, 0, stream>>>(xl, xr, att1, bias1,
                                                            offs, srcs, hb);

    // layer 2
    gemm_dual_mfma<<<GG, 256, 0, stream>>>(hb, w2lh, w2ll, w2rh, w2rl,
                                           b2l, b2r, xl, xr, NODES);
    node_pass<1, false><<<(NODES + 3) / 4, 256, 0, stream>>>(xl, xr, att2, bias2,
                                                             offs, srcs, out);
}

// Round 5
// 409.443 us; speedup vs baseline: 1.3577x; 1.0095x over previous
//
#include <hip/hip_runtime.h>
#include <hip/hip_bf16.h>

#define NODES 50000
#define NEDGE 800000
#define CH 128          // all of IN/HID/OUT
#define NEG_SLOPE 0.2f
#define SCAN_CHUNK 2048
#define NBLK ((NODES + SCAN_CHUNK - 1) / SCAN_CHUNK)   // 25
#define NINF -1.0e30f
#define LOG2E 1.44269504088896340736f

typedef short short8 __attribute__((ext_vector_type(8)));
typedef float f32x4 __attribute__((ext_vector_type(4)));

__device__ __forceinline__ unsigned fbits(float f) {
    union { float f; unsigned u; } v; v.f = f; return v.u;
}
__device__ __forceinline__ float asf(unsigned u) {
    union { float f; unsigned u; } v; v.u = u; return v.f;
}
// fp32 -> bf16 (RNE), for W prep only
__device__ __forceinline__ unsigned short f2bf(float f) {
    unsigned u = fbits(f);
    unsigned r = u + 0x7fff + ((u >> 16) & 1);
    return (unsigned short)(r >> 16);
}
__device__ __forceinline__ float bf2f(unsigned short h) {
    return asf(((unsigned)h) << 16);
}
// lrelu(x) = max(x, 0.2x)  (valid since 0 < slope < 1)
__device__ __forceinline__ float lrelu(float x) {
    return fmaxf(x, NEG_SLOPE * x);
}

// ---------------------------------------------------------------------------
// edge_index dtype detection (int64 vs int32)
// ---------------------------------------------------------------------------
__global__ void detect_i64_kernel(const void* idx, int* flag) {
    const int* w = (const int*)idx;
    int nz = (w[2 * threadIdx.x + 1] != 0) ? 1 : 0;
    unsigned long long b = __ballot(nz);
    if (threadIdx.x == 0) *flag = (b == 0ull) ? 1 : 0;
}

__device__ __forceinline__ int edge_at(const void* idx, int i64, int pos) {
    return i64 ? (int)((const long long*)idx)[pos] : ((const int*)idx)[pos];
}

// ---------------------------------------------------------------------------
// CSR build: histogram of dst, 3-phase parallel exclusive scan, scatter src
// ---------------------------------------------------------------------------
__global__ void hist_kernel(const void* idx, const int* flag, int* cnt) {
    int e = blockIdx.x * blockDim.x + threadIdx.x;
    if (e >= NEDGE) return;
    int dst = edge_at(idx, *flag, NEDGE + e);
    atomicAdd(&cnt[dst], 1);
}

__global__ __launch_bounds__(256) void scan1_kernel(const int* __restrict__ cnt,
                                                    int* __restrict__ bsum) {
    int base = blockIdx.x * SCAN_CHUNK + (int)threadIdx.x * 8;
    int s = 0;
    #pragma unroll
    for (int k = 0; k < 8; ++k) {
        int i = base + k;
        s += (i < NODES) ? cnt[i] : 0;
    }
    #pragma unroll
    for (int m = 1; m < 64; m <<= 1) s += __shfl_xor(s, m);
    __shared__ int ws[4];
    if ((threadIdx.x & 63) == 0) ws[threadIdx.x >> 6] = s;
    __syncthreads();
    if (threadIdx.x == 0) bsum[blockIdx.x] = ws[0] + ws[1] + ws[2] + ws[3];
}

__global__ void scan2_kernel(const int* __restrict__ bsum, int* __restrict__ boff,
                             int* __restrict__ offs) {
    if (threadIdx.x == 0) {
        int acc = 0;
        for (int b = 0; b < NBLK; ++b) { boff[b] = acc; acc += bsum[b]; }
        offs[NODES] = acc;      // == NEDGE
    }
}

__global__ __launch_bounds__(256) void scan3_kernel(const int* __restrict__ cnt,
                                                    const int* __restrict__ boff,
                                                    int* __restrict__ offs,
                                                    int* __restrict__ cursor) {
    int tid = (int)threadIdx.x;
    int base = blockIdx.x * SCAN_CHUNK + tid * 8;
    int v[8];
    int s = 0;
    #pragma unroll
    for (int k = 0; k < 8; ++k) {
        int i = base + k;
        v[k] = (i < NODES) ? cnt[i] : 0;
        s += v[k];
    }
    int lane = tid & 63;
    int incl = s;
    #pragma unroll
    for (int m = 1; m < 64; m <<= 1) {
        int t = __shfl_up(incl, m);
        if (lane >= m) incl += t;
    }
    __shared__ int wtot[4];
    if (lane == 63) wtot[tid >> 6] = incl;
    __syncthreads();
    int w = tid >> 6;
    int wbase = 0;
    #pragma unroll
    for (int k = 0; k < 4; ++k) wbase += (k < w) ? wtot[k] : 0;
    int excl = boff[blockIdx.x] + wbase + (incl - s);
    #pragma unroll
    for (int k = 0; k < 8; ++k) {
        int i = base + k;
        if (i < NODES) { offs[i] = excl; cursor[i] = excl; }
        excl += v[k];
    }
}

__global__ void scatter_kernel(const void* idx, const int* flag,
                               int* cursor, int* __restrict__ srcs) {
    int e = blockIdx.x * blockDim.x + threadIdx.x;
    if (e >= NEDGE) return;
    int i64 = *flag;
    int s = edge_at(idx, i64, e);
    int d = edge_at(idx, i64, NEDGE + e);
    int pos = atomicAdd(&cursor[d], 1);
    srcs[pos] = s;
}

// ---------------------------------------------------------------------------
// W prep (all 4 W's in one launch): fp32 [k][n] -> transposed [n][k] bf16
// hi/lo (RNE split). Per W: hi[16384] then lo[16384] shorts at stride 32768.
// ---------------------------------------------------------------------------
__global__ __launch_bounds__(256) void wprep4_kernel(const float* __restrict__ W0,
                                                     const float* __restrict__ W1,
                                                     const float* __restrict__ W2,
                                                     const float* __restrict__ W3,
                                                     unsigned short* __restrict__ base) {
    int which = blockIdx.x >> 6;                 // 64 blocks per W
    const float* W = (which == 0) ? W0 : (which == 1) ? W1 : (which == 2) ? W2 : W3;
    unsigned short* hiT = base + (size_t)which * 32768;
    unsigned short* loT = hiT + 16384;
    int i = (blockIdx.x & 63) * 256 + (int)threadIdx.x;   // 0..16383
    int k = i >> 7, n = i & 127;
    float f = W[i];
    unsigned short h = f2bf(f);
    unsigned short l = f2bf(f - bf2f(h));
    hiT[n * CH + k] = h;
    loT[n * CH + k] = l;
}

// ---------------------------------------------------------------------------
// Split-bf16 MFMA dual GEMM: Yl = X@Wl + bl, Yr = X@Wr + br.
// X@W = Xh@Wh + Xl@Wh + Xh@Wl (lo@lo dropped, ~2^-16 rel).
// X staged as truncation-split bf16 (hi = top 16 bits, lo = trunc(f - hi));
// packed uint2 LDS writes (ds_write_b64), 3 VALU/elem.
// ---------------------------------------------------------------------------
#define GR 64
#define LDP 136   // padded row stride in shorts (272 B, 8B-aligned)

__global__ __launch_bounds__(256) void gemm_dual_mfma(
        const float* __restrict__ X,
        const unsigned short* __restrict__ whTl, const unsigned short* __restrict__ wlTl,
        const unsigned short* __restrict__ whTr, const unsigned short* __restrict__ wlTr,
        const float* __restrict__ bl, const float* __restrict__ br,
        float* __restrict__ Yl, float* __restrict__ Yr, int nrows) {
    __shared__ unsigned short xh[GR][LDP];
    __shared__ unsigned short xlo[GR][LDP];

    int r0 = blockIdx.x * GR;
    int tid = (int)threadIdx.x;

    // ---- stage X tile: fp32 -> hi/lo bf16 (truncation split), packed ----
    {
        int row = tid >> 2;              // 0..63
        int c0 = (tid & 3) * 32;         // col start
        const float* src = X + (size_t)(r0 + row) * CH + c0;
        bool valid = (r0 + row) < nrows;
        #pragma unroll
        for (int j = 0; j < 32; j += 4) {
            float4 v = valid ? *(const float4*)(src + j)
                             : make_float4(0.f, 0.f, 0.f, 0.f);
            unsigned ux = fbits(v.x), uy = fbits(v.y);
            unsigned uz = fbits(v.z), uw = fbits(v.w);
            unsigned hx = ux & 0xFFFF0000u, hy = uy & 0xFFFF0000u;
            unsigned hz = uz & 0xFFFF0000u, hw = uw & 0xFFFF0000u;
            uint2 hp;
            hp.x = (ux >> 16) | hy;
            hp.y = (uz >> 16) | hw;
            float lx = v.x - asf(hx), ly = v.y - asf(hy);
            float lz = v.z - asf(hz), lw = v.w - asf(hw);
            uint2 lp;
            lp.x = (fbits(lx) >> 16) | (fbits(ly) & 0xFFFF0000u);
            lp.y = (fbits(lz) >> 16) | (fbits(lw) & 0xFFFF0000u);
            *(uint2*)&xh[row][c0 + j]  = hp;
            *(uint2*)&xlo[row][c0 + j] = lp;
        }
    }
    __syncthreads();

    int wave = tid >> 6;      // 0..3: n-quarter
    int lane = tid & 63;
    int l15 = lane & 15, q = lane >> 4;

    f32x4 acc[4][4];
    #pragma unroll
    for (int mt = 0; mt < 4; ++mt)
        #pragma unroll
        for (int nt = 0; nt < 4; ++nt) acc[mt][nt] = (f32x4)0.f;

    const unsigned short* bhp[4];
    const unsigned short* blp_[4];
    int ncol[4];
    #pragma unroll
    for (int nt = 0; nt < 4; ++nt) {
        int n = (wave * 4 + nt) * 16 + l15;       // 0..255
        ncol[nt] = n;
        int nn = n & 127;
        bhp[nt]  = ((n < CH) ? whTl : whTr) + (size_t)nn * CH;
        blp_[nt] = ((n < CH) ? wlTl : wlTr) + (size_t)nn * CH;
    }

    for (int kt = 0; kt < 4; ++kt) {
        int kofs = kt * 32 + q * 8;
        short8 ah[4], al[4];
        #pragma unroll
        for (int mt = 0; mt < 4; ++mt) {
            ah[mt] = *(const short8*)&xh[mt * 16 + l15][kofs];
            al[mt] = *(const short8*)&xlo[mt * 16 + l15][kofs];
        }
        #pragma unroll
        for (int nt = 0; nt < 4; ++nt) {
            short8 bh8 = *(const short8*)(bhp[nt] + kofs);
            short8 bl8 = *(const short8*)(blp_[nt] + kofs);
            #pragma unroll
            for (int mt = 0; mt < 4; ++mt) {
                acc[mt][nt] = __builtin_amdgcn_mfma_f32_16x16x32_bf16(
                                  ah[mt], bh8, acc[mt][nt], 0, 0, 0);
                acc[mt][nt] = __builtin_amdgcn_mfma_f32_16x16x32_bf16(
                                  al[mt], bh8, acc[mt][nt], 0, 0, 0);
                acc[mt][nt] = __builtin_amdgcn_mfma_f32_16x16x32_bf16(
                                  ah[mt], bl8, acc[mt][nt], 0, 0, 0);
            }
        }
    }

    // ---- epilogue: C/D layout col=lane&15, row=q*4+reg ----
    #pragma unroll
    for (int nt = 0; nt < 4; ++nt) {
        int n = ncol[nt];
        float* Y = (n < CH) ? Yl : Yr;
        int nc = n & 127;
        float bv = (n < CH) ? bl[nc] : br[nc];
        #pragma unroll
        for (int mt = 0; mt < 4; ++mt) {
            #pragma unroll
            for (int reg = 0; reg < 4; ++reg) {
                int row = r0 + mt * 16 + q * 4 + reg;
                if (row < nrows)
                    Y[(size_t)row * CH + nc] = acc[mt][nt][reg] + bv;
            }
        }
    }
}

// ---------------------------------------------------------------------------
// Fused GATv2 edge pass, v3: 4 waves/block, one node per wave; 32 lanes per
// edge row (float4/lane); two independent half-wave online-softmax states
// (4 edges in flight) + software prefetch of the next edge pair (clamped to
// end-1, so prefetch traffic is never wasted). att pre-scaled by log2e so
// softmax uses raw v_exp_f32 (exp2).
// ---------------------------------------------------------------------------
template <int HEADS, bool RELU>
__global__ __launch_bounds__(256) void node_pass(
        const float* __restrict__ xl, const float* __restrict__ xr,
        const float* __restrict__ att,    // 128 floats, flat (H, C/H)
        const float* __restrict__ bias,   // 128 floats
        const int* __restrict__ offs, const int* __restrict__ srcs,
        float* __restrict__ out) {
    constexpr int GL = (CH / HEADS) / 4;     // lanes per head group: 8 or 32
    int wave = (int)threadIdx.x >> 6;
    int i = blockIdx.x * 4 + wave;
    int lane = (int)threadIdx.x & 63;
    int half = lane >> 5;
    int l32 = lane & 31;

    float4 r  = ((const float4*)(xr + (size_t)i * CH))[l32];
    float4 at = ((const float4*)att)[l32];
    at.x *= LOG2E; at.y *= LOG2E; at.z *= LOG2E; at.w *= LOG2E;
    float4 xs = ((const float4*)(xl + (size_t)i * CH))[l32];

    // self-loop logit (scaled domain)
    float ts = lrelu(xs.x + r.x) * at.x + lrelu(xs.y + r.y) * at.y
             + lrelu(xs.z + r.z) * at.z + lrelu(xs.w + r.w) * at.w;
    #pragma unroll
    for (int msk = 1; msk < GL; msk <<= 1) ts += __shfl_xor(ts, msk);

    float  m = (half == 0) ? ts : NINF;
    float  d = (half == 0) ? 1.f : 0.f;
    float4 acc;
    acc.x = (half == 0) ? xs.x : 0.f;  acc.y = (half == 0) ? xs.y : 0.f;
    acc.z = (half == 0) ? xs.z : 0.f;  acc.w = (half == 0) ? xs.w : 0.f;

    int beg = offs[i], end = offs[i + 1];
    int deg = end - beg;
    int iters = (deg + 3) >> 2;
    if (iters > 0) {
        int last = end - 1;
        int e0 = beg + half * 2;
        int sa = srcs[min(e0, last)];
        int sb = srcs[min(e0 + 1, last)];
        float4 a0 = ((const float4*)(xl + (size_t)sa * CH))[l32];
        float4 a1 = ((const float4*)(xl + (size_t)sb * CH))[l32];

        for (int it = 0; it < iters; ++it, e0 += 4) {
            bool va = e0 < end, vb = (e0 + 1) < end;
            // prefetch next pair (clamped: always this node's own edges)
            int sn0 = srcs[min(e0 + 4, last)];
            int sn1 = srcs[min(e0 + 5, last)];
            float4 n0 = ((const float4*)(xl + (size_t)sn0 * CH))[l32];
            float4 n1 = ((const float4*)(xl + (size_t)sn1 * CH))[l32];

            float t0 = lrelu(a0.x + r.x) * at.x + lrelu(a0.y + r.y) * at.y
                     + lrelu(a0.z + r.z) * at.z + lrelu(a0.w + r.w) * at.w;
            float t1 = lrelu(a1.x + r.x) * at.x + lrelu(a1.y + r.y) * at.y
                     + lrelu(a1.z + r.z) * at.z + lrelu(a1.w + r.w) * at.w;
            #pragma unroll
            for (int msk = 1; msk < GL; msk <<= 1) {
                t0 += __shfl_xor(t0, msk);
                t1 += __shfl_xor(t1, msk);
            }
            t0 = va ? t0 : NINF;
            t1 = vb ? t1 : NINF;

            float nm = fmaxf(m, fmaxf(t0, t1));
            float sc = exp2f(m - nm);
            float p0 = va ? exp2f(t0 - nm) : 0.f;
            float p1 = vb ? exp2f(t1 - nm) : 0.f;
            d = d * sc + p0 + p1;
            acc.x = acc.x * sc + p0 * a0.x + p1 * a1.x;
            acc.y = acc.y * sc + p0 * a0.y + p1 * a1.y;
            acc.z = acc.z * sc + p0 * a0.z + p1 * a1.z;
            acc.w = acc.w * sc + p0 * a0.w + p1 * a1.w;
            m = nm;
            a0 = n0; a1 = n1;
        }
    }

    // merge the two half-wave states
    float mo = __shfl_xor(m, 32);
    float do_ = __shfl_xor(d, 32);
    float4 ao;
    ao.x = __shfl_xor(acc.x, 32); ao.y = __shfl_xor(acc.y, 32);
    ao.z = __shfl_xor(acc.z, 32); ao.w = __shfl_xor(acc.w, 32);
    float mt = fmaxf(m, mo);
    float s0 = exp2f(m - mt), s1 = exp2f(mo - mt);
    float dt = d * s0 + do_ * s1;
    float inv = 1.0f / dt;

    float4 bb = ((const float4*)bias)[l32];
    float4 ot;
    ot.x = (acc.x * s0 + ao.x * s1) * inv + bb.x;
    ot.y = (acc.y * s0 + ao.y * s1) * inv + bb.y;
    ot.z = (acc.z * s0 + ao.z * s1) * inv + bb.z;
    ot.w = (acc.w * s0 + ao.w * s1) * inv + bb.w;
    if (RELU) {
        ot.x = fmaxf(ot.x, 0.f); ot.y = fmaxf(ot.y, 0.f);
        ot.z = fmaxf(ot.z, 0.f); ot.w = fmaxf(ot.w, 0.f);
    }
    if (half == 0)
        ((float4*)(out + (size_t)i * CH))[l32] = ot;
}

// ---------------------------------------------------------------------------
extern "C" void kernel_launch(void* const* d_in, const int* in_sizes, int n_in,
                              void* d_out, int out_size, void* d_ws, size_t ws_size,
                              hipStream_t stream) {
    const float* x     = (const float*)d_in[0];
    const void*  eidx  = d_in[1];
    const float* W1l   = (const float*)d_in[2];
    const float* b1l   = (const float*)d_in[3];
    const float* W1r   = (const float*)d_in[4];
    const float* b1r   = (const float*)d_in[5];
    const float* att1  = (const float*)d_in[6];
    const float* bias1 = (const float*)d_in[7];
    const float* W2l   = (const float*)d_in[8];
    const float* b2l   = (const float*)d_in[9];
    const float* W2r   = (const float*)d_in[10];
    const float* b2r   = (const float*)d_in[11];
    const float* att2  = (const float*)d_in[12];
    const float* bias2 = (const float*)d_in[13];
    float* out = (float*)d_out;

    // workspace layout
    float* xl = (float*)d_ws;                       // N*128
    float* xr = xl + (size_t)NODES * CH;            // N*128
    float* hb = xr + (size_t)NODES * CH;            // N*128
    int* offs   = (int*)(hb + (size_t)NODES * CH);  // N+1
    int* cnt    = offs + (NODES + 1);               // N  (reused as W bf16 buf)
    int* cursor = cnt + NODES;                      // N  (reused as W bf16 buf)
    int* srcs   = cursor + NODES;                   // E
    int* flag   = srcs + NEDGE;                     // 1
    int* bsum   = flag + 1;                         // NBLK
    int* boff   = bsum + NBLK;                      // NBLK

    // After scatter, cnt+cursor (400 KB) are dead -> reuse for bf16 W's.
    unsigned short* wbuf = (unsigned short*)cnt;
    unsigned short* w1lh = wbuf;              unsigned short* w1ll = wbuf + 16384;
    unsigned short* w1rh = wbuf + 32768;      unsigned short* w1rl = wbuf + 49152;
    unsigned short* w2lh = wbuf + 65536;      unsigned short* w2ll = wbuf + 81920;
    unsigned short* w2rh = wbuf + 98304;      unsigned short* w2rl = wbuf + 114688;

    const int EB = 256, EG = (NEDGE + EB - 1) / EB;
    const int GG = (NODES + GR - 1) / GR;

    // CSR build
    hipMemsetAsync(cnt, 0, (size_t)NODES * sizeof(int), stream);
    detect_i64_kernel<<<1, 64, 0, stream>>>(eidx, flag);
    hist_kernel<<<EG, EB, 0, stream>>>(eidx, flag, cnt);
    scan1_kernel<<<NBLK, 256, 0, stream>>>(cnt, bsum);
    scan2_kernel<<<1, 64, 0, stream>>>(bsum, boff, offs);
    scan3_kernel<<<NBLK, 256, 0, stream>>>(cnt, boff, offs, cursor);
    scatter_kernel<<<EG, EB, 0, stream>>>(eidx, flag, cursor, srcs);

    // W -> bf16 hi/lo transposed (cnt/cursor dead after scatter)
    wprep4_kernel<<<256, 256, 0, stream>>>(W1l, W1r, W2l, W2r, wbuf);

    // layer 1
    gemm_dual_mfma<<<GG, 256, 0, stream>>>(x, w1lh, w1ll, w1rh, w1rl,
                                           b1l, b1r, xl, xr, NODES);
    node_pass<4, true><<<(NODES + 3) / 4, 256, 0, stream>>>(xl, xr, att1, bias1,
                                                            offs, srcs, hb);

    // layer 2
    gemm_dual_mfma<<<GG, 256, 0, stream>>>(hb, w2lh, w2ll, w2rh, w2rl,
                                           b2l, b2r, xl, xr, NODES);
    node_pass<1, false><<<(NODES + 3) / 4, 256, 0, stream>>>(xl, xr, att2, bias2,
                                                             offs, srcs, out);
}

// Round 6
// 376.303 us; speedup vs baseline: 1.4772x; 1.0881x over previous
//
#include <hip/hip_runtime.h>
#include <hip/hip_bf16.h>

#define NODES 50000
#define NEDGE 800000
#define CH 128          // all of IN/HID/OUT
#define NEG_SLOPE 0.2f
#define SCAN_CHUNK 2048
#define NBLK ((NODES + SCAN_CHUNK - 1) / SCAN_CHUNK)   // 25
#define NINF -1.0e30f
#define LOG2E 1.44269504088896340736f

typedef short short8 __attribute__((ext_vector_type(8)));
typedef float f32x4 __attribute__((ext_vector_type(4)));

__device__ __forceinline__ unsigned fbits(float f) {
    union { float f; unsigned u; } v; v.f = f; return v.u;
}
__device__ __forceinline__ float asf(unsigned u) {
    union { float f; unsigned u; } v; v.u = u; return v.f;
}
// fp32 -> bf16 (RNE)
__device__ __forceinline__ unsigned short f2bf(float f) {
    unsigned u = fbits(f);
    unsigned r = u + 0x7fff + ((u >> 16) & 1);
    return (unsigned short)(r >> 16);
}
__device__ __forceinline__ float bf2f(unsigned short h) {
    return asf(((unsigned)h) << 16);
}
__device__ __forceinline__ float lrelu(float x) {
    return fmaxf(x, NEG_SLOPE * x);
}
// 8 bf16 (as uint4) -> 8 fp32
__device__ __forceinline__ void bf8cvt(uint4 u, float* f) {
    f[0] = asf(u.x << 16); f[1] = asf(u.x & 0xFFFF0000u);
    f[2] = asf(u.y << 16); f[3] = asf(u.y & 0xFFFF0000u);
    f[4] = asf(u.z << 16); f[5] = asf(u.z & 0xFFFF0000u);
    f[6] = asf(u.w << 16); f[7] = asf(u.w & 0xFFFF0000u);
}

// ---------------------------------------------------------------------------
// detect edge dtype (int64 vs int32) + zero the histogram, one launch
// ---------------------------------------------------------------------------
__global__ __launch_bounds__(256) void detect_zero_kernel(const void* idx,
                                                          int* flag, int* cnt) {
    int t = blockIdx.x * 256 + (int)threadIdx.x;
    if (t < NODES) cnt[t] = 0;
    if (blockIdx.x == 0 && threadIdx.x < 64) {
        const int* w = (const int*)idx;
        int nz = (w[2 * threadIdx.x + 1] != 0) ? 1 : 0;
        unsigned long long b = __ballot(nz);
        if (threadIdx.x == 0) *flag = (b == 0ull) ? 1 : 0;
    }
}

__device__ __forceinline__ int edge_at(const void* idx, int i64, int pos) {
    return i64 ? (int)((const long long*)idx)[pos] : ((const int*)idx)[pos];
}

// ---------------------------------------------------------------------------
// CSR build: histogram of dst, 2-kernel parallel exclusive scan, scatter src
// ---------------------------------------------------------------------------
__global__ void hist_kernel(const void* idx, const int* flag, int* cnt) {
    int e = blockIdx.x * blockDim.x + threadIdx.x;
    if (e >= NEDGE) return;
    int dst = edge_at(idx, *flag, NEDGE + e);
    atomicAdd(&cnt[dst], 1);
}

__global__ __launch_bounds__(256) void scan1_kernel(const int* __restrict__ cnt,
                                                    int* __restrict__ bsum) {
    int base = blockIdx.x * SCAN_CHUNK + (int)threadIdx.x * 8;
    int s = 0;
    #pragma unroll
    for (int k = 0; k < 8; ++k) {
        int i = base + k;
        s += (i < NODES) ? cnt[i] : 0;
    }
    #pragma unroll
    for (int m = 1; m < 64; m <<= 1) s += __shfl_xor(s, m);
    __shared__ int ws[4];
    if ((threadIdx.x & 63) == 0) ws[threadIdx.x >> 6] = s;
    __syncthreads();
    if (threadIdx.x == 0) bsum[blockIdx.x] = ws[0] + ws[1] + ws[2] + ws[3];
}

// per-block exclusive scan + global offset (block prefix computed in-kernel)
__global__ __launch_bounds__(256) void scan3_kernel(const int* __restrict__ cnt,
                                                    const int* __restrict__ bsum,
                                                    int* __restrict__ offs,
                                                    int* __restrict__ cursor) {
    int tid = (int)threadIdx.x;
    int bpre = 0;
    #pragma unroll
    for (int b = 0; b < NBLK; ++b) bpre += (b < (int)blockIdx.x) ? bsum[b] : 0;

    int base = blockIdx.x * SCAN_CHUNK + tid * 8;
    int v[8];
    int s = 0;
    #pragma unroll
    for (int k = 0; k < 8; ++k) {
        int i = base + k;
        v[k] = (i < NODES) ? cnt[i] : 0;
        s += v[k];
    }
    int lane = tid & 63;
    int incl = s;
    #pragma unroll
    for (int m = 1; m < 64; m <<= 1) {
        int t = __shfl_up(incl, m);
        if (lane >= m) incl += t;
    }
    __shared__ int wtot[4];
    if (lane == 63) wtot[tid >> 6] = incl;
    __syncthreads();
    int w = tid >> 6;
    int wbase = 0;
    #pragma unroll
    for (int k = 0; k < 4; ++k) wbase += (k < w) ? wtot[k] : 0;
    int excl = bpre + wbase + (incl - s);
    #pragma unroll
    for (int k = 0; k < 8; ++k) {
        int i = base + k;
        if (i < NODES) { offs[i] = excl; cursor[i] = excl; }
        excl += v[k];
    }
    if (blockIdx.x == 0 && tid == 0) offs[NODES] = NEDGE;
}

__global__ void scatter_kernel(const void* idx, const int* flag,
                               int* cursor, int* __restrict__ srcs) {
    int e = blockIdx.x * blockDim.x + threadIdx.x;
    if (e >= NEDGE) return;
    int i64 = *flag;
    int s = edge_at(idx, i64, e);
    int d = edge_at(idx, i64, NEDGE + e);
    int pos = atomicAdd(&cursor[d], 1);
    srcs[pos] = s;
}

// ---------------------------------------------------------------------------
// W prep (all 4 W's in one launch): fp32 [k][n] -> transposed [n][k] bf16
// hi/lo (RNE split). Per W: hi[16384] then lo[16384] shorts at stride 32768.
// ---------------------------------------------------------------------------
__global__ __launch_bounds__(256) void wprep4_kernel(const float* __restrict__ W0,
                                                     const float* __restrict__ W1,
                                                     const float* __restrict__ W2,
                                                     const float* __restrict__ W3,
                                                     unsigned short* __restrict__ base) {
    int which = blockIdx.x >> 6;                 // 64 blocks per W
    const float* W = (which == 0) ? W0 : (which == 1) ? W1 : (which == 2) ? W2 : W3;
    unsigned short* hiT = base + (size_t)which * 32768;
    unsigned short* loT = hiT + 16384;
    int i = (blockIdx.x & 63) * 256 + (int)threadIdx.x;   // 0..16383
    int k = i >> 7, n = i & 127;
    float f = W[i];
    unsigned short h = f2bf(f);
    unsigned short l = f2bf(f - bf2f(h));
    hiT[n * CH + k] = h;
    loT[n * CH + k] = l;
}

// ---------------------------------------------------------------------------
// Split-bf16 MFMA dual GEMM: Ylb = bf16(X@Wl + bl)  [attention-side, gathered
// later so stored bf16], Yr = X@Wr + br (fp32).
// X@W = Xh@Wh + Xl@Wh + Xh@Wl (lo@lo dropped).
// ---------------------------------------------------------------------------
#define GR 64
#define LDP 136   // padded row stride in shorts (272 B)

__global__ __launch_bounds__(256) void gemm_dual_mfma(
        const float* __restrict__ X,
        const unsigned short* __restrict__ whTl, const unsigned short* __restrict__ wlTl,
        const unsigned short* __restrict__ whTr, const unsigned short* __restrict__ wlTr,
        const float* __restrict__ bl, const float* __restrict__ br,
        unsigned short* __restrict__ Ylb, float* __restrict__ Yr, int nrows) {
    __shared__ unsigned short xh[GR][LDP];
    __shared__ unsigned short xlo[GR][LDP];

    int r0 = blockIdx.x * GR;
    int tid = (int)threadIdx.x;

    // ---- stage X tile: fp32 -> hi/lo bf16 (truncation split), packed ----
    {
        int row = tid >> 2;              // 0..63
        int c0 = (tid & 3) * 32;         // col start
        const float* src = X + (size_t)(r0 + row) * CH + c0;
        bool valid = (r0 + row) < nrows;
        #pragma unroll
        for (int j = 0; j < 32; j += 4) {
            float4 v = valid ? *(const float4*)(src + j)
                             : make_float4(0.f, 0.f, 0.f, 0.f);
            unsigned ux = fbits(v.x), uy = fbits(v.y);
            unsigned uz = fbits(v.z), uw = fbits(v.w);
            unsigned hx = ux & 0xFFFF0000u, hy = uy & 0xFFFF0000u;
            unsigned hz = uz & 0xFFFF0000u, hw = uw & 0xFFFF0000u;
            uint2 hp;
            hp.x = (ux >> 16) | hy;
            hp.y = (uz >> 16) | hw;
            float lx = v.x - asf(hx), ly = v.y - asf(hy);
            float lz = v.z - asf(hz), lw = v.w - asf(hw);
            uint2 lp;
            lp.x = (fbits(lx) >> 16) | (fbits(ly) & 0xFFFF0000u);
            lp.y = (fbits(lz) >> 16) | (fbits(lw) & 0xFFFF0000u);
            *(uint2*)&xh[row][c0 + j]  = hp;
            *(uint2*)&xlo[row][c0 + j] = lp;
        }
    }
    __syncthreads();

    int wave = tid >> 6;      // 0..3: n-quarter
    int lane = tid & 63;
    int l15 = lane & 15, q = lane >> 4;

    f32x4 acc[4][4];
    #pragma unroll
    for (int mt = 0; mt < 4; ++mt)
        #pragma unroll
        for (int nt = 0; nt < 4; ++nt) acc[mt][nt] = (f32x4)0.f;

    const unsigned short* bhp[4];
    const unsigned short* blp_[4];
    int ncol[4];
    #pragma unroll
    for (int nt = 0; nt < 4; ++nt) {
        int n = (wave * 4 + nt) * 16 + l15;       // 0..255
        ncol[nt] = n;
        int nn = n & 127;
        bhp[nt]  = ((n < CH) ? whTl : whTr) + (size_t)nn * CH;
        blp_[nt] = ((n < CH) ? wlTl : wlTr) + (size_t)nn * CH;
    }

    for (int kt = 0; kt < 4; ++kt) {
        int kofs = kt * 32 + q * 8;
        short8 ah[4], al[4];
        #pragma unroll
        for (int mt = 0; mt < 4; ++mt) {
            ah[mt] = *(const short8*)&xh[mt * 16 + l15][kofs];
            al[mt] = *(const short8*)&xlo[mt * 16 + l15][kofs];
        }
        #pragma unroll
        for (int nt = 0; nt < 4; ++nt) {
            short8 bh8 = *(const short8*)(bhp[nt] + kofs);
            short8 bl8 = *(const short8*)(blp_[nt] + kofs);
            #pragma unroll
            for (int mt = 0; mt < 4; ++mt) {
                acc[mt][nt] = __builtin_amdgcn_mfma_f32_16x16x32_bf16(
                                  ah[mt], bh8, acc[mt][nt], 0, 0, 0);
                acc[mt][nt] = __builtin_amdgcn_mfma_f32_16x16x32_bf16(
                                  al[mt], bh8, acc[mt][nt], 0, 0, 0);
                acc[mt][nt] = __builtin_amdgcn_mfma_f32_16x16x32_bf16(
                                  ah[mt], bl8, acc[mt][nt], 0, 0, 0);
            }
        }
    }

    // ---- epilogue: C/D layout col=lane&15, row=q*4+reg ----
    #pragma unroll
    for (int nt = 0; nt < 4; ++nt) {
        int n = ncol[nt];
        int nc = n & 127;
        if (n < CH) {
            float bv = bl[nc];
            #pragma unroll
            for (int mt = 0; mt < 4; ++mt)
                #pragma unroll
                for (int reg = 0; reg < 4; ++reg) {
                    int row = r0 + mt * 16 + q * 4 + reg;
                    if (row < nrows)
                        Ylb[(size_t)row * CH + nc] = f2bf(acc[mt][nt][reg] + bv);
                }
        } else {
            float bv = br[nc];
            #pragma unroll
            for (int mt = 0; mt < 4; ++mt)
                #pragma unroll
                for (int reg = 0; reg < 4; ++reg) {
                    int row = r0 + mt * 16 + q * 4 + reg;
                    if (row < nrows)
                        Yr[(size_t)row * CH + nc] = acc[mt][nt][reg] + bv;
                }
        }
    }
}

// ---------------------------------------------------------------------------
// Fused GATv2 edge pass, v4: one node per wave; 16 lanes per edge row
// (8 bf16 channels per lane via one uint4); FOUR independent quarter-wave
// online-softmax states (4 edges per VMEM instruction), merged via
// shfl_xor 16/32. xl gathered in bf16 (256 B/row). att pre-scaled by log2e.
// ---------------------------------------------------------------------------
template <int HEADS, bool RELU>
__global__ __launch_bounds__(256) void node_pass(
        const unsigned short* __restrict__ xlb,   // [N][128] bf16 bits
        const float* __restrict__ xr,
        const float* __restrict__ att,    // 128 floats, flat (H, C/H)
        const float* __restrict__ bias,   // 128 floats
        const int* __restrict__ offs, const int* __restrict__ srcs,
        float* __restrict__ out) {
    constexpr int GL = (CH / HEADS) / 8;     // lanes per head group: 4 or 16
    int wave = (int)threadIdx.x >> 6;
    int i = blockIdx.x * 4 + wave;
    int lane = (int)threadIdx.x & 63;
    int g = lane >> 4;                       // edge-group 0..3
    int l16 = lane & 15;
    int c0 = l16 * 8;                        // first of this lane's 8 channels

    float r[8], a[8], s[8];
    {
        const float4* xrp = (const float4*)(xr + (size_t)i * CH + c0);
        float4 r0 = xrp[0], r1 = xrp[1];
        r[0]=r0.x; r[1]=r0.y; r[2]=r0.z; r[3]=r0.w;
        r[4]=r1.x; r[5]=r1.y; r[6]=r1.z; r[7]=r1.w;
        const float4* atp = (const float4*)(att + c0);
        float4 a0 = atp[0], a1 = atp[1];
        a[0]=a0.x*LOG2E; a[1]=a0.y*LOG2E; a[2]=a0.z*LOG2E; a[3]=a0.w*LOG2E;
        a[4]=a1.x*LOG2E; a[5]=a1.y*LOG2E; a[6]=a1.z*LOG2E; a[7]=a1.w*LOG2E;
    }
    // self row (bf16)
    uint4 us = *(const uint4*)(xlb + (size_t)i * CH + c0);
    bf8cvt(us, s);

    float ts = 0.f;
    #pragma unroll
    for (int c = 0; c < 8; ++c) ts += lrelu(s[c] + r[c]) * a[c];
    #pragma unroll
    for (int msk = 1; msk < GL; msk <<= 1) ts += __shfl_xor(ts, msk);

    float m = (g == 0) ? ts : NINF;
    float d = (g == 0) ? 1.f : 0.f;
    float acc[8];
    #pragma unroll
    for (int c = 0; c < 8; ++c) acc[c] = (g == 0) ? s[c] : 0.f;

    int beg = offs[i], end = offs[i + 1];
    int deg = end - beg;
    int iters = (deg + 3) >> 2;
    if (iters > 0) {
        int last = end - 1;
        int e = beg + g;
        int si = srcs[min(e, last)];
        uint4 u = *(const uint4*)(xlb + (size_t)si * CH + c0);

        for (int it = 0; it < iters; ++it, e += 4) {
            bool valid = e < end;
            // prefetch next edge for this group (clamped: own segment only)
            int sn = srcs[min(e + 4, last)];
            uint4 un = *(const uint4*)(xlb + (size_t)sn * CH + c0);

            float f[8];
            bf8cvt(u, f);
            float t = 0.f;
            #pragma unroll
            for (int c = 0; c < 8; ++c) t += lrelu(f[c] + r[c]) * a[c];
            #pragma unroll
            for (int msk = 1; msk < GL; msk <<= 1) t += __shfl_xor(t, msk);
            t = valid ? t : NINF;

            float nm = fmaxf(m, t);
            float sc = exp2f(m - nm);
            float p  = valid ? exp2f(t - nm) : 0.f;
            d = d * sc + p;
            #pragma unroll
            for (int c = 0; c < 8; ++c) acc[c] = acc[c] * sc + p * f[c];
            m = nm;
            u = un;
        }
    }

    // merge the 4 quarter-wave states (butterfly: all lanes converge)
    #pragma unroll
    for (int msk = 16; msk <= 32; msk <<= 1) {
        float mo  = __shfl_xor(m, msk);
        float dof = __shfl_xor(d, msk);
        float nm = fmaxf(m, mo);
        float s0 = exp2f(m - nm), s1 = exp2f(mo - nm);
        d = d * s0 + dof * s1;
        #pragma unroll
        for (int c = 0; c < 8; ++c) {
            float ao = __shfl_xor(acc[c], msk);
            acc[c] = acc[c] * s0 + ao * s1;
        }
        m = nm;
    }

    if (g == 0) {
        float inv = 1.0f / d;
        const float4* bp = (const float4*)(bias + c0);
        float4 b0 = bp[0], b1 = bp[1];
        float bb[8] = {b0.x, b0.y, b0.z, b0.w, b1.x, b1.y, b1.z, b1.w};
        float o[8];
        #pragma unroll
        for (int c = 0; c < 8; ++c) {
            o[c] = acc[c] * inv + bb[c];
            if (RELU) o[c] = fmaxf(o[c], 0.f);
        }
        float4 w0 = make_float4(o[0], o[1], o[2], o[3]);
        float4 w1 = make_float4(o[4], o[5], o[6], o[7]);
        float4* op = (float4*)(out + (size_t)i * CH + c0);
        op[0] = w0; op[1] = w1;
    }
}

// ---------------------------------------------------------------------------
extern "C" void kernel_launch(void* const* d_in, const int* in_sizes, int n_in,
                              void* d_out, int out_size, void* d_ws, size_t ws_size,
                              hipStream_t stream) {
    const float* x     = (const float*)d_in[0];
    const void*  eidx  = d_in[1];
    const float* W1l   = (const float*)d_in[2];
    const float* b1l   = (const float*)d_in[3];
    const float* W1r   = (const float*)d_in[4];
    const float* b1r   = (const float*)d_in[5];
    const float* att1  = (const float*)d_in[6];
    const float* bias1 = (const float*)d_in[7];
    const float* W2l   = (const float*)d_in[8];
    const float* b2l   = (const float*)d_in[9];
    const float* W2r   = (const float*)d_in[10];
    const float* b2r   = (const float*)d_in[11];
    const float* att2  = (const float*)d_in[12];
    const float* bias2 = (const float*)d_in[13];
    float* out = (float*)d_out;

    // workspace layout
    unsigned short* xlb = (unsigned short*)d_ws;    // N*128 bf16
    float* xr = (float*)(xlb + (size_t)NODES * CH); // N*128 fp32
    float* hb = xr + (size_t)NODES * CH;            // N*128 fp32
    int* offs   = (int*)(hb + (size_t)NODES * CH);  // N+1
    int* cnt    = offs + (NODES + 1);               // N  (reused as W bf16 buf)
    int* cursor = cnt + NODES;                      // N  (reused as W bf16 buf)
    int* srcs   = cursor + NODES;                   // E
    int* flag   = srcs + NEDGE;                     // 1
    int* bsum   = flag + 1;                         // NBLK

    // After scatter, cnt+cursor (400 KB) are dead -> reuse for bf16 W's.
    unsigned short* wbuf = (unsigned short*)cnt;
    unsigned short* w1lh = wbuf;              unsigned short* w1ll = wbuf + 16384;
    unsigned short* w1rh = wbuf + 32768;      unsigned short* w1rl = wbuf + 49152;
    unsigned short* w2lh = wbuf + 65536;      unsigned short* w2ll = wbuf + 81920;
    unsigned short* w2rh = wbuf + 98304;      unsigned short* w2rl = wbuf + 114688;

    const int EB = 256, EG = (NEDGE + EB - 1) / EB;
    const int GG = (NODES + GR - 1) / GR;
    const int ZB = (NODES + 255) / 256;

    // CSR build
    detect_zero_kernel<<<ZB, 256, 0, stream>>>(eidx, flag, cnt);
    hist_kernel<<<EG, EB, 0, stream>>>(eidx, flag, cnt);
    scan1_kernel<<<NBLK, 256, 0, stream>>>(cnt, bsum);
    scan3_kernel<<<NBLK, 256, 0, stream>>>(cnt, bsum, offs, cursor);
    scatter_kernel<<<EG, EB, 0, stream>>>(eidx, flag, cursor, srcs);

    // W -> bf16 hi/lo transposed (cnt/cursor dead after scatter)
    wprep4_kernel<<<256, 256, 0, stream>>>(W1l, W1r, W2l, W2r, wbuf);

    // layer 1
    gemm_dual_mfma<<<GG, 256, 0, stream>>>(x, w1lh, w1ll, w1rh, w1rl,
                                           b1l, b1r, xlb, xr, NODES);
    node_pass<4, true><<<(NODES + 3) / 4, 256, 0, stream>>>(xlb, xr, att1, bias1,
                                                            offs, srcs, hb);

    // layer 2
    gemm_dual_mfma<<<GG, 256, 0, stream>>>(hb, w2lh, w2ll, w2rh, w2rl,
                                           b2l, b2r, xlb, xr, NODES);
    node_pass<1, false><<<(NODES + 3) / 4, 256, 0, stream>>>(xlb, xr, att2, bias2,
                                                             offs, srcs, out);
}

// Round 7
// 365.523 us; speedup vs baseline: 1.5208x; 1.0295x over previous
//
#include <hip/hip_runtime.h>
#include <hip/hip_bf16.h>

#define NODES 50000
#define NEDGE 800000
#define CH 128          // all of IN/HID/OUT
#define NEG_SLOPE 0.2f
#define SCAN_CHUNK 2048
#define NBLK ((NODES + SCAN_CHUNK - 1) / SCAN_CHUNK)   // 25
#define NINF -1.0e30f
#define LOG2E 1.44269504088896340736f
#define NSLICE 400
#define SSLICE (NEDGE / NSLICE)       // 2000 edges per slice

typedef short short8 __attribute__((ext_vector_type(8)));
typedef float f32x4 __attribute__((ext_vector_type(4)));

__device__ __forceinline__ unsigned fbits(float f) {
    union { float f; unsigned u; } v; v.f = f; return v.u;
}
__device__ __forceinline__ float asf(unsigned u) {
    union { float f; unsigned u; } v; v.u = u; return v.f;
}
// fp32 -> bf16 (RNE)
__device__ __forceinline__ unsigned short f2bf(float f) {
    unsigned u = fbits(f);
    unsigned r = u + 0x7fff + ((u >> 16) & 1);
    return (unsigned short)(r >> 16);
}
__device__ __forceinline__ float bf2f(unsigned short h) {
    return asf(((unsigned)h) << 16);
}
__device__ __forceinline__ float lrelu(float x) {
    return fmaxf(x, NEG_SLOPE * x);
}
// 8 bf16 (as uint4) -> 8 fp32
__device__ __forceinline__ void bf8cvt(uint4 u, float* f) {
    f[0] = asf(u.x << 16); f[1] = asf(u.x & 0xFFFF0000u);
    f[2] = asf(u.y << 16); f[3] = asf(u.y & 0xFFFF0000u);
    f[4] = asf(u.z << 16); f[5] = asf(u.z & 0xFFFF0000u);
    f[6] = asf(u.w << 16); f[7] = asf(u.w & 0xFFFF0000u);
}
// dst-range set for XCD-partitioned CSR build
__device__ __forceinline__ int dset(int dst) {
    return (int)(((unsigned)dst * 8u) / 50000u);   // exact partition of [0,50000)
}

// ---------------------------------------------------------------------------
// detect edge dtype (int64 vs int32) + zero the histogram, one launch
// ---------------------------------------------------------------------------
__global__ __launch_bounds__(256) void detect_zero_kernel(const void* idx,
                                                          int* flag, int* cnt) {
    int t = blockIdx.x * 256 + (int)threadIdx.x;
    if (t < NODES) cnt[t] = 0;
    if (blockIdx.x == 0 && threadIdx.x < 64) {
        const int* w = (const int*)idx;
        int nz = (w[2 * threadIdx.x + 1] != 0) ? 1 : 0;
        unsigned long long b = __ballot(nz);
        if (threadIdx.x == 0) *flag = (b == 0ull) ? 1 : 0;
    }
}

// ---------------------------------------------------------------------------
// XCD-partitioned histogram: block (slice, set=blockIdx&7) scans its slice,
// counts only dst in its set's range. Consecutive blockIdx round-robin over
// XCDs, so each cnt line is touched by ~one XCD -> no L2 line bouncing.
// (dst values < 2^31: low 32-bit word suffices even for int64 input.)
// ---------------------------------------------------------------------------
__global__ __launch_bounds__(256) void hist_part_kernel(const void* idx,
                                                        const int* flag,
                                                        int* cnt) {
    int set = blockIdx.x & 7;
    int slice = blockIdx.x >> 3;
    int base = slice * SSLICE;
    int endE = base + SSLICE;
    int i64 = *flag;
    const int* w = (const int*)idx;
    for (int e = base + (int)threadIdx.x; e < endE; e += 256) {
        int dst = i64 ? w[2 * (NEDGE + e)] : w[NEDGE + e];
        if (dset(dst) == set) atomicAdd(&cnt[dst], 1);
    }
}

__global__ __launch_bounds__(256) void scan1_kernel(const int* __restrict__ cnt,
                                                    int* __restrict__ bsum) {
    int base = blockIdx.x * SCAN_CHUNK + (int)threadIdx.x * 8;
    int s = 0;
    #pragma unroll
    for (int k = 0; k < 8; ++k) {
        int i = base + k;
        s += (i < NODES) ? cnt[i] : 0;
    }
    #pragma unroll
    for (int m = 1; m < 64; m <<= 1) s += __shfl_xor(s, m);
    __shared__ int ws[4];
    if ((threadIdx.x & 63) == 0) ws[threadIdx.x >> 6] = s;
    __syncthreads();
    if (threadIdx.x == 0) bsum[blockIdx.x] = ws[0] + ws[1] + ws[2] + ws[3];
}

// per-block exclusive scan + global offset (block prefix computed in-kernel)
__global__ __launch_bounds__(256) void scan3_kernel(const int* __restrict__ cnt,
                                                    const int* __restrict__ bsum,
                                                    int* __restrict__ offs,
                                                    int* __restrict__ cursor) {
    int tid = (int)threadIdx.x;
    int bpre = 0;
    #pragma unroll
    for (int b = 0; b < NBLK; ++b) bpre += (b < (int)blockIdx.x) ? bsum[b] : 0;

    int base = blockIdx.x * SCAN_CHUNK + tid * 8;
    int v[8];
    int s = 0;
    #pragma unroll
    for (int k = 0; k < 8; ++k) {
        int i = base + k;
        v[k] = (i < NODES) ? cnt[i] : 0;
        s += v[k];
    }
    int lane = tid & 63;
    int incl = s;
    #pragma unroll
    for (int m = 1; m < 64; m <<= 1) {
        int t = __shfl_up(incl, m);
        if (lane >= m) incl += t;
    }
    __shared__ int wtot[4];
    if (lane == 63) wtot[tid >> 6] = incl;
    __syncthreads();
    int w = tid >> 6;
    int wbase = 0;
    #pragma unroll
    for (int k = 0; k < 4; ++k) wbase += (k < w) ? wtot[k] : 0;
    int excl = bpre + wbase + (incl - s);
    #pragma unroll
    for (int k = 0; k < 8; ++k) {
        int i = base + k;
        if (i < NODES) { offs[i] = excl; cursor[i] = excl; }
        excl += v[k];
    }
    if (blockIdx.x == 0 && tid == 0) offs[NODES] = NEDGE;
}

// ---------------------------------------------------------------------------
// XCD-partitioned scatter: same (slice, set) decomposition. All srcs/cursor
// traffic for a dst range comes from one XCD's blocks -> lines stay in that
// XCD's L2 (WRITE_SIZE ~3 MB instead of 52 MB of line bounces).
// ---------------------------------------------------------------------------
__global__ __launch_bounds__(256) void scatter_part_kernel(const void* idx,
                                                           const int* flag,
                                                           int* cursor,
                                                           int* __restrict__ srcs) {
    int set = blockIdx.x & 7;
    int slice = blockIdx.x >> 3;
    int base = slice * SSLICE;
    int endE = base + SSLICE;
    int i64 = *flag;
    const int* w = (const int*)idx;
    for (int e = base + (int)threadIdx.x; e < endE; e += 256) {
        int dst = i64 ? w[2 * (NEDGE + e)] : w[NEDGE + e];
        if (dset(dst) == set) {
            int src = i64 ? w[2 * e] : w[e];
            int pos = atomicAdd(&cursor[dst], 1);
            srcs[pos] = src;
        }
    }
}

// ---------------------------------------------------------------------------
// W prep (all 4 W's in one launch): fp32 [k][n] -> transposed [n][k] bf16
// hi/lo (RNE split). Per W: hi[16384] then lo[16384] shorts at stride 32768.
// ---------------------------------------------------------------------------
__global__ __launch_bounds__(256) void wprep4_kernel(const float* __restrict__ W0,
                                                     const float* __restrict__ W1,
                                                     const float* __restrict__ W2,
                                                     const float* __restrict__ W3,
                                                     unsigned short* __restrict__ base) {
    int which = blockIdx.x >> 6;                 // 64 blocks per W
    const float* W = (which == 0) ? W0 : (which == 1) ? W1 : (which == 2) ? W2 : W3;
    unsigned short* hiT = base + (size_t)which * 32768;
    unsigned short* loT = hiT + 16384;
    int i = (blockIdx.x & 63) * 256 + (int)threadIdx.x;   // 0..16383
    int k = i >> 7, n = i & 127;
    float f = W[i];
    unsigned short h = f2bf(f);
    unsigned short l = f2bf(f - bf2f(h));
    hiT[n * CH + k] = h;
    loT[n * CH + k] = l;
}

// ---------------------------------------------------------------------------
// Split-bf16 MFMA dual GEMM: Ylb = bf16(X@Wl + bl), Yr = X@Wr + br (fp32).
// X@W = Xh@Wh + Xl@Wh + Xh@Wl (lo@lo dropped).
// ---------------------------------------------------------------------------
#define GR 64
#define LDP 136   // padded row stride in shorts (272 B)

__global__ __launch_bounds__(256) void gemm_dual_mfma(
        const float* __restrict__ X,
        const unsigned short* __restrict__ whTl, const unsigned short* __restrict__ wlTl,
        const unsigned short* __restrict__ whTr, const unsigned short* __restrict__ wlTr,
        const float* __restrict__ bl, const float* __restrict__ br,
        unsigned short* __restrict__ Ylb, float* __restrict__ Yr, int nrows) {
    __shared__ unsigned short xh[GR][LDP];
    __shared__ unsigned short xlo[GR][LDP];

    int r0 = blockIdx.x * GR;
    int tid = (int)threadIdx.x;

    // ---- stage X tile: fp32 -> hi/lo bf16 (truncation split), packed ----
    {
        int row = tid >> 2;              // 0..63
        int c0 = (tid & 3) * 32;         // col start
        const float* src = X + (size_t)(r0 + row) * CH + c0;
        bool valid = (r0 + row) < nrows;
        #pragma unroll
        for (int j = 0; j < 32; j += 4) {
            float4 v = valid ? *(const float4*)(src + j)
                             : make_float4(0.f, 0.f, 0.f, 0.f);
            unsigned ux = fbits(v.x), uy = fbits(v.y);
            unsigned uz = fbits(v.z), uw = fbits(v.w);
            unsigned hx = ux & 0xFFFF0000u, hy = uy & 0xFFFF0000u;
            unsigned hz = uz & 0xFFFF0000u, hw = uw & 0xFFFF0000u;
            uint2 hp;
            hp.x = (ux >> 16) | hy;
            hp.y = (uz >> 16) | hw;
            float lx = v.x - asf(hx), ly = v.y - asf(hy);
            float lz = v.z - asf(hz), lw = v.w - asf(hw);
            uint2 lp;
            lp.x = (fbits(lx) >> 16) | (fbits(ly) & 0xFFFF0000u);
            lp.y = (fbits(lz) >> 16) | (fbits(lw) & 0xFFFF0000u);
            *(uint2*)&xh[row][c0 + j]  = hp;
            *(uint2*)&xlo[row][c0 + j] = lp;
        }
    }
    __syncthreads();

    int wave = tid >> 6;      // 0..3: n-quarter
    int lane = tid & 63;
    int l15 = lane & 15, q = lane >> 4;

    f32x4 acc[4][4];
    #pragma unroll
    for (int mt = 0; mt < 4; ++mt)
        #pragma unroll
        for (int nt = 0; nt < 4; ++nt) acc[mt][nt] = (f32x4)0.f;

    const unsigned short* bhp[4];
    const unsigned short* blp_[4];
    int ncol[4];
    #pragma unroll
    for (int nt = 0; nt < 4; ++nt) {
        int n = (wave * 4 + nt) * 16 + l15;       // 0..255
        ncol[nt] = n;
        int nn = n & 127;
        bhp[nt]  = ((n < CH) ? whTl : whTr) + (size_t)nn * CH;
        blp_[nt] = ((n < CH) ? wlTl : wlTr) + (size_t)nn * CH;
    }

    for (int kt = 0; kt < 4; ++kt) {
        int kofs = kt * 32 + q * 8;
        short8 ah[4], al[4];
        #pragma unroll
        for (int mt = 0; mt < 4; ++mt) {
            ah[mt] = *(const short8*)&xh[mt * 16 + l15][kofs];
            al[mt] = *(const short8*)&xlo[mt * 16 + l15][kofs];
        }
        #pragma unroll
        for (int nt = 0; nt < 4; ++nt) {
            short8 bh8 = *(const short8*)(bhp[nt] + kofs);
            short8 bl8 = *(const short8*)(blp_[nt] + kofs);
            #pragma unroll
            for (int mt = 0; mt < 4; ++mt) {
                acc[mt][nt] = __builtin_amdgcn_mfma_f32_16x16x32_bf16(
                                  ah[mt], bh8, acc[mt][nt], 0, 0, 0);
                acc[mt][nt] = __builtin_amdgcn_mfma_f32_16x16x32_bf16(
                                  al[mt], bh8, acc[mt][nt], 0, 0, 0);
                acc[mt][nt] = __builtin_amdgcn_mfma_f32_16x16x32_bf16(
                                  ah[mt], bl8, acc[mt][nt], 0, 0, 0);
            }
        }
    }

    // ---- epilogue: C/D layout col=lane&15, row=q*4+reg ----
    #pragma unroll
    for (int nt = 0; nt < 4; ++nt) {
        int n = ncol[nt];
        int nc = n & 127;
        if (n < CH) {
            float bv = bl[nc];
            #pragma unroll
            for (int mt = 0; mt < 4; ++mt)
                #pragma unroll
                for (int reg = 0; reg < 4; ++reg) {
                    int row = r0 + mt * 16 + q * 4 + reg;
                    if (row < nrows)
                        Ylb[(size_t)row * CH + nc] = f2bf(acc[mt][nt][reg] + bv);
                }
        } else {
            float bv = br[nc];
            #pragma unroll
            for (int mt = 0; mt < 4; ++mt)
                #pragma unroll
                for (int reg = 0; reg < 4; ++reg) {
                    int row = r0 + mt * 16 + q * 4 + reg;
                    if (row < nrows)
                        Yr[(size_t)row * CH + nc] = acc[mt][nt][reg] + bv;
                }
        }
    }
}

// ---------------------------------------------------------------------------
// Fused GATv2 edge pass: one node per wave; 16 lanes per edge row (8 bf16
// channels per lane via one uint4); four quarter-wave online-softmax states
// (4 edges per VMEM instruction) merged via shfl_xor 16/32. att pre-scaled
// by log2e so all exps are raw v_exp_f32.
// ---------------------------------------------------------------------------
template <int HEADS, bool RELU>
__global__ __launch_bounds__(256) void node_pass(
        const unsigned short* __restrict__ xlb,   // [N][128] bf16 bits
        const float* __restrict__ xr,
        const float* __restrict__ att,    // 128 floats, flat (H, C/H)
        const float* __restrict__ bias,   // 128 floats
        const int* __restrict__ offs, const int* __restrict__ srcs,
        float* __restrict__ out) {
    constexpr int GL = (CH / HEADS) / 8;     // lanes per head group: 4 or 16
    int wave = (int)threadIdx.x >> 6;
    int i = blockIdx.x * 4 + wave;
    int lane = (int)threadIdx.x & 63;
    int g = lane >> 4;                       // edge-group 0..3
    int l16 = lane & 15;
    int c0 = l16 * 8;                        // first of this lane's 8 channels

    float r[8], a[8], s[8];
    {
        const float4* xrp = (const float4*)(xr + (size_t)i * CH + c0);
        float4 r0 = xrp[0], r1 = xrp[1];
        r[0]=r0.x; r[1]=r0.y; r[2]=r0.z; r[3]=r0.w;
        r[4]=r1.x; r[5]=r1.y; r[6]=r1.z; r[7]=r1.w;
        const float4* atp = (const float4*)(att + c0);
        float4 a0 = atp[0], a1 = atp[1];
        a[0]=a0.x*LOG2E; a[1]=a0.y*LOG2E; a[2]=a0.z*LOG2E; a[3]=a0.w*LOG2E;
        a[4]=a1.x*LOG2E; a[5]=a1.y*LOG2E; a[6]=a1.z*LOG2E; a[7]=a1.w*LOG2E;
    }
    // self row (bf16)
    uint4 us = *(const uint4*)(xlb + (size_t)i * CH + c0);
    bf8cvt(us, s);

    float ts = 0.f;
    #pragma unroll
    for (int c = 0; c < 8; ++c) ts += lrelu(s[c] + r[c]) * a[c];
    #pragma unroll
    for (int msk = 1; msk < GL; msk <<= 1) ts += __shfl_xor(ts, msk);

    float m = (g == 0) ? ts : NINF;
    float d = (g == 0) ? 1.f : 0.f;
    float acc[8];
    #pragma unroll
    for (int c = 0; c < 8; ++c) acc[c] = (g == 0) ? s[c] : 0.f;

    int beg = offs[i], end = offs[i + 1];
    int deg = end - beg;
    int iters = (deg + 3) >> 2;
    if (iters > 0) {
        int last = end - 1;
        int e = beg + g;
        int si = srcs[min(e, last)];
        uint4 u = *(const uint4*)(xlb + (size_t)si * CH + c0);

        for (int it = 0; it < iters; ++it, e += 4) {
            bool valid = e < end;
            // prefetch next edge for this group (clamped: own segment only)
            int sn = srcs[min(e + 4, last)];
            uint4 un = *(const uint4*)(xlb + (size_t)sn * CH + c0);

            float f[8];
            bf8cvt(u, f);
            float t = 0.f;
            #pragma unroll
            for (int c = 0; c < 8; ++c) t += lrelu(f[c] + r[c]) * a[c];
            #pragma unroll
            for (int msk = 1; msk < GL; msk <<= 1) t += __shfl_xor(t, msk);
            t = valid ? t : NINF;

            float nm = fmaxf(m, t);
            float sc = exp2f(m - nm);
            float p  = valid ? exp2f(t - nm) : 0.f;
            d = d * sc + p;
            #pragma unroll
            for (int c = 0; c < 8; ++c) acc[c] = acc[c] * sc + p * f[c];
            m = nm;
            u = un;
        }
    }

    // merge the 4 quarter-wave states (butterfly: all lanes converge)
    #pragma unroll
    for (int msk = 16; msk <= 32; msk <<= 1) {
        float mo  = __shfl_xor(m, msk);
        float dof = __shfl_xor(d, msk);
        float nm = fmaxf(m, mo);
        float s0 = exp2f(m - nm), s1 = exp2f(mo - nm);
        d = d * s0 + dof * s1;
        #pragma unroll
        for (int c = 0; c < 8; ++c) {
            float ao = __shfl_xor(acc[c], msk);
            acc[c] = acc[c] * s0 + ao * s1;
        }
        m = nm;
    }

    if (g == 0) {
        float inv = 1.0f / d;
        const float4* bp = (const float4*)(bias + c0);
        float4 b0 = bp[0], b1 = bp[1];
        float bb[8] = {b0.x, b0.y, b0.z, b0.w, b1.x, b1.y, b1.z, b1.w};
        float o[8];
        #pragma unroll
        for (int c = 0; c < 8; ++c) {
            o[c] = acc[c] * inv + bb[c];
            if (RELU) o[c] = fmaxf(o[c], 0.f);
        }
        float4 w0 = make_float4(o[0], o[1], o[2], o[3]);
        float4 w1 = make_float4(o[4], o[5], o[6], o[7]);
        float4* op = (float4*)(out + (size_t)i * CH + c0);
        op[0] = w0; op[1] = w1;
    }
}

// ---------------------------------------------------------------------------
extern "C" void kernel_launch(void* const* d_in, const int* in_sizes, int n_in,
                              void* d_out, int out_size, void* d_ws, size_t ws_size,
                              hipStream_t stream) {
    const float* x     = (const float*)d_in[0];
    const void*  eidx  = d_in[1];
    const float* W1l   = (const float*)d_in[2];
    const float* b1l   = (const float*)d_in[3];
    const float* W1r   = (const float*)d_in[4];
    const float* b1r   = (const float*)d_in[5];
    const float* att1  = (const float*)d_in[6];
    const float* bias1 = (const float*)d_in[7];
    const float* W2l   = (const float*)d_in[8];
    const float* b2l   = (const float*)d_in[9];
    const float* W2r   = (const float*)d_in[10];
    const float* b2r   = (const float*)d_in[11];
    const float* att2  = (const float*)d_in[12];
    const float* bias2 = (const float*)d_in[13];
    float* out = (float*)d_out;

    // workspace layout
    unsigned short* xlb = (unsigned short*)d_ws;    // N*128 bf16
    float* xr = (float*)(xlb + (size_t)NODES * CH); // N*128 fp32
    float* hb = xr + (size_t)NODES * CH;            // N*128 fp32
    int* offs   = (int*)(hb + (size_t)NODES * CH);  // N+1
    int* cnt    = offs + (NODES + 1);               // N  (reused as W bf16 buf)
    int* cursor = cnt + NODES;                      // N  (reused as W bf16 buf)
    int* srcs   = cursor + NODES;                   // E
    int* flag   = srcs + NEDGE;                     // 1
    int* bsum   = flag + 1;                         // NBLK

    // After scatter, cnt+cursor (400 KB) are dead -> reuse for bf16 W's.
    unsigned short* wbuf = (unsigned short*)cnt;
    unsigned short* w1lh = wbuf;              unsigned short* w1ll = wbuf + 16384;
    unsigned short* w1rh = wbuf + 32768;      unsigned short* w1rl = wbuf + 49152;
    unsigned short* w2lh = wbuf + 65536;      unsigned short* w2ll = wbuf + 81920;
    unsigned short* w2rh = wbuf + 98304;      unsigned short* w2rl = wbuf + 114688;

    const int GG = (NODES + GR - 1) / GR;
    const int ZB = (NODES + 255) / 256;
    const int PG = NSLICE * 8;               // partitioned hist/scatter grid

    // CSR build (XCD-partitioned hist + scatter)
    detect_zero_kernel<<<ZB, 256, 0, stream>>>(eidx, flag, cnt);
    hist_part_kernel<<<PG, 256, 0, stream>>>(eidx, flag, cnt);
    scan1_kernel<<<NBLK, 256, 0, stream>>>(cnt, bsum);
    scan3_kernel<<<NBLK, 256, 0, stream>>>(cnt, bsum, offs, cursor);
    scatter_part_kernel<<<PG, 256, 0, stream>>>(eidx, flag, cursor, srcs);

    // W -> bf16 hi/lo transposed (cnt/cursor dead after scatter)
    wprep4_kernel<<<256, 256, 0, stream>>>(W1l, W1r, W2l, W2r, wbuf);

    // layer 1
    gemm_dual_mfma<<<GG, 256, 0, stream>>>(x, w1lh, w1ll, w1rh, w1rl,
                                           b1l, b1r, xlb, xr, NODES);
    node_pass<4, true><<<(NODES + 3) / 4, 256, 0, stream>>>(xlb, xr, att1, bias1,
                                                            offs, srcs, hb);

    // layer 2
    gemm_dual_mfma<<<GG, 256, 0, stream>>>(hb, w2lh, w2ll, w2rh, w2rl,
                                           b2l, b2r, xlb, xr, NODES);
    node_pass<1, false><<<(NODES + 3) / 4, 256, 0, stream>>>(xlb, xr, att2, bias2,
                                                             offs, srcs, out);
}